// Round 1
// baseline (151.816 us; speedup 1.0000x reference)
//
#include <hip/hip_runtime.h>
#include <math.h>

#define HD 512
#define BB 4
#define TT 128
#define SS 512

typedef __attribute__((ext_vector_type(8))) short short8;
typedef __attribute__((ext_vector_type(4))) float floatx4;
typedef _Float16 half2_t __attribute__((ext_vector_type(2)));
typedef unsigned short ushort_t;
typedef unsigned int uint_t;

__device__ __forceinline__ float tanh_e(float x) {
    float t = __builtin_amdgcn_rcpf(__expf(2.f * x) + 1.f);
    return fmaf(-2.f, t, 1.f);
}
__device__ __forceinline__ ushort_t f2bf(float x) {      // RNE fp32->bf16
    unsigned int u = __float_as_uint(x);
    u += 0x7fffu + ((u >> 16) & 1u);
    return (ushort_t)(u >> 16);
}

// ---- Kernel 0: prep. W->bf16 [n][k] transposed (coalesced); query->cq right; enc->bf16 ----
// grid: 128 W-blocks (128k x 64n tiles) + 128 query blocks + 512 enc blocks = 768
__global__ __launch_bounds__(256) void wtrans_kernel(
    const float* __restrict__ Ws, const float* __restrict__ Wh,
    const float* __restrict__ Wo, const float* __restrict__ query,
    const float* __restrict__ enc,
    ushort_t* __restrict__ Ts, ushort_t* __restrict__ Th, ushort_t* __restrict__ To,
    ushort_t* __restrict__ cq, ushort_t* __restrict__ encB)
{
    const int bid = blockIdx.x;
    const int tid = threadIdx.x;
    if (bid < 128) {
        const float* src; ushort_t* dst; int K, l;
        if (bid < 32)      { src = Ws; dst = Ts; K = 512;  l = bid;      }
        else if (bid < 64) { src = Wh; dst = Th; K = 512;  l = bid - 32; }
        else               { src = Wo; dst = To; K = 1024; l = bid - 64; }
        const int ktiles = K >> 7;
        const int tk = l & (ktiles - 1), tn = l / ktiles;
        const int k0 = tk * 128, n0 = tn * 64;

        __shared__ ushort_t tile[64][136];     // [n][k], row 272B (16B aligned)

        const int lr  = tid >> 4;              // 0..15
        const int lc4 = (tid & 15) * 4;        // 0..60
        #pragma unroll
        for (int p = 0; p < 8; ++p) {
            const int row = p * 16 + lr;       // k-local
            float4 s = *(const float4*)(src + (size_t)(k0 + row) * HD + n0 + lc4);
            tile[lc4 + 0][row] = f2bf(s.x);
            tile[lc4 + 1][row] = f2bf(s.y);
            tile[lc4 + 2][row] = f2bf(s.z);
            tile[lc4 + 3][row] = f2bf(s.w);
        }
        __syncthreads();
        const int n = tid >> 2, kc = (tid & 3) * 32;
        #pragma unroll
        for (int j = 0; j < 4; ++j) {
            uint4 o = *(const uint4*)&tile[n][kc + j * 8];
            *(uint4*)&dst[(size_t)(n0 + n) * K + k0 + kc + j * 8] = o;
        }
    } else if (bid < 256) {
        // query -> bf16 into cq[m][512 + h]
        const int idx = ((bid - 128) * 256 + tid) * 8;
        const int m = idx >> 9, h = idx & 511;
        float4 q0 = *(const float4*)(query + (size_t)m * HD + h);
        float4 q1 = *(const float4*)(query + (size_t)m * HD + h + 4);
        uint4 o;
        o.x = (uint_t)f2bf(q0.x) | ((uint_t)f2bf(q0.y) << 16);
        o.y = (uint_t)f2bf(q0.z) | ((uint_t)f2bf(q0.w) << 16);
        o.z = (uint_t)f2bf(q1.x) | ((uint_t)f2bf(q1.y) << 16);
        o.w = (uint_t)f2bf(q1.z) | ((uint_t)f2bf(q1.w) << 16);
        *(uint4*)&cq[(size_t)m * 1024 + 512 + h] = o;
    } else {
        // enc -> bf16 encB (row-major)
        const size_t idx = ((size_t)(bid - 256) * 256 + tid) * 8;
        float4 e0 = *(const float4*)(enc + idx);
        float4 e1 = *(const float4*)(enc + idx + 4);
        uint4 o;
        o.x = (uint_t)f2bf(e0.x) | ((uint_t)f2bf(e0.y) << 16);
        o.y = (uint_t)f2bf(e0.z) | ((uint_t)f2bf(e0.w) << 16);
        o.z = (uint_t)f2bf(e1.x) | ((uint_t)f2bf(e1.y) << 16);
        o.w = (uint_t)f2bf(e1.z) | ((uint_t)f2bf(e1.w) << 16);
        *(uint4*)&encB[idx] = o;
    }
}

// ---- Kernel 1: MFMA proj, 4 GEMM families in one launch (grid 80 x 8):
//   bm  0..7 : tqa  = {tanh(q@Ws), v*tanh(q@Ws)}  fp32 pairs
//   bm 8..39 : peT  = fp16(tanh(enc@Wh))^T  (B,H,S)
//   bm 40..71: encWo= fp16(enc@Wo_a)        (B,S,H) row-major
//   bm 72..79: qWob = fp32(q@Wo_b)          (B*T,H)
#define LDP 40
__global__ __launch_bounds__(256) void proj_kernel(
    const ushort_t* __restrict__ cq, const ushort_t* __restrict__ encB,
    const ushort_t* __restrict__ WTs, const ushort_t* __restrict__ WTh,
    const ushort_t* __restrict__ WTo, const float* __restrict__ v,
    float2* __restrict__ tqa, _Float16* __restrict__ peT,
    _Float16* __restrict__ encWo, float* __restrict__ qWob)
{
    const int bm = blockIdx.x;            // 0..79
    const int bn = blockIdx.y;            // 0..7
    int type; const ushort_t* A; int lda; const ushort_t* B; int ldb; int m0;
    if (bm < 8)       { type = 0; A = cq + 512; lda = 1024; B = WTs;       ldb = 512;  m0 = bm * 64;        }
    else if (bm < 40) { type = 1; A = encB;     lda = 512;  B = WTh;       ldb = 512;  m0 = (bm - 8) * 64;  }
    else if (bm < 72) { type = 2; A = encB;     lda = 512;  B = WTo;       ldb = 1024; m0 = (bm - 40) * 64; }
    else              { type = 3; A = cq + 512; lda = 1024; B = WTo + 512; ldb = 1024; m0 = (bm - 72) * 64; }
    const int n0 = bn * 64;

    __shared__ ushort_t As[64 * LDP];     // [m][k]
    __shared__ ushort_t Bs[64 * LDP];     // [n][k]

    const int tid = threadIdx.x;
    const int lane = tid & 63, w = tid >> 6;
    const int quad = lane >> 4, lrow = lane & 15;
    const int mw = (w & 1) * 32, nw = (w >> 1) * 32;

    const int ar = tid >> 2;              // 0..63
    const int ac = (tid & 3) * 8;         // 0,8,16,24

    floatx4 zero = {0.f, 0.f, 0.f, 0.f};
    floatx4 acc[2][2] = {{zero, zero}, {zero, zero}};

    uint4 ald = *(const uint4*)&A[(size_t)(m0 + ar) * lda + ac];
    uint4 bld = *(const uint4*)&B[(size_t)(n0 + ar) * ldb + ac];

    for (int k0 = 0; k0 < HD; k0 += 32) {
        __syncthreads();
        *(uint4*)&As[ar * LDP + ac] = ald;
        *(uint4*)&Bs[ar * LDP + ac] = bld;
        __syncthreads();
        if (k0 + 32 < HD) {
            ald = *(const uint4*)&A[(size_t)(m0 + ar) * lda + k0 + 32 + ac];
            bld = *(const uint4*)&B[(size_t)(n0 + ar) * ldb + k0 + 32 + ac];
        }
        short8 af[2], bf[2];
        #pragma unroll
        for (int i = 0; i < 2; ++i)
            af[i] = *(const short8*)&As[(mw + i * 16 + lrow) * LDP + quad * 8];
        #pragma unroll
        for (int j = 0; j < 2; ++j)
            bf[j] = *(const short8*)&Bs[(nw + j * 16 + lrow) * LDP + quad * 8];
        #pragma unroll
        for (int i = 0; i < 2; ++i)
            #pragma unroll
            for (int j = 0; j < 2; ++j)
                acc[i][j] = __builtin_amdgcn_mfma_f32_16x16x32_bf16(af[i], bf[j], acc[i][j], 0, 0, 0);
    }

    if (type == 0) {
        #pragma unroll
        for (int j = 0; j < 2; ++j) {
            const int col = n0 + nw + j * 16 + lrow;
            const float vj = v[col];
            #pragma unroll
            for (int i = 0; i < 2; ++i)
                #pragma unroll
                for (int r = 0; r < 4; ++r) {
                    const int row = m0 + mw + i * 16 + quad * 4 + r;
                    float tq = tanh_e(acc[i][j][r]);
                    float2 o; o.x = tq; o.y = vj * tq;
                    tqa[(size_t)row * HD + col] = o;
                }
        }
    } else if (type == 1) {
        #pragma unroll
        for (int i = 0; i < 2; ++i)
            #pragma unroll
            for (int j = 0; j < 2; ++j) {
                const int gm = m0 + mw + i * 16 + quad * 4;
                const int b = gm >> 9, s = gm & 511;
                const int col = n0 + nw + j * 16 + lrow;
                _Float16 t0 = (_Float16)tanh_e(acc[i][j][0]);
                _Float16 t1 = (_Float16)tanh_e(acc[i][j][1]);
                _Float16 t2 = (_Float16)tanh_e(acc[i][j][2]);
                _Float16 t3 = (_Float16)tanh_e(acc[i][j][3]);
                ushort4 o;
                o.x = *(ushort_t*)&t0; o.y = *(ushort_t*)&t1;
                o.z = *(ushort_t*)&t2; o.w = *(ushort_t*)&t3;
                *(ushort4*)((ushort_t*)peT + ((size_t)b * HD + col) * SS + s) = o;
            }
    } else if (type == 2) {
        // encWo[b*S+s][n] fp16 row-major
        #pragma unroll
        for (int i = 0; i < 2; ++i)
            #pragma unroll
            for (int j = 0; j < 2; ++j) {
                const int col = n0 + nw + j * 16 + lrow;
                #pragma unroll
                for (int r = 0; r < 4; ++r) {
                    const int gm = m0 + mw + i * 16 + quad * 4 + r;
                    encWo[(size_t)gm * HD + col] = (_Float16)acc[i][j][r];
                }
            }
    } else {
        // qWob[b*T+t][n] fp32 (no activation)
        #pragma unroll
        for (int i = 0; i < 2; ++i)
            #pragma unroll
            for (int j = 0; j < 2; ++j) {
                const int col = n0 + nw + j * 16 + lrow;
                #pragma unroll
                for (int r = 0; r < 4; ++r) {
                    const int gm = m0 + mw + i * 16 + quad * 4 + r;
                    qWob[(size_t)gm * HD + col] = acc[i][j][r];
                }
            }
    }
}

// ---- Kernel 2: fused score + softmax + output row. One block per (b,t). ----
//  phase A: scores s=2*tid,2*tid+1 over all 512 h (tanh-addition formula)
//  phase B: in-block softmax -> alpha fp32 in LDS
//  phase C: out[n=2*tid,2*tid+1] = tanh(sum_s alpha_s*encWo[b,s,n] + qWob[bt,n])
__global__ __launch_bounds__(256) void fused_kernel(
    const float2* __restrict__ tqa, const _Float16* __restrict__ peT,
    const float* __restrict__ vv, const _Float16* __restrict__ encWo,
    const float* __restrict__ qWob, const int* __restrict__ lens,
    float* __restrict__ out)
{
    const int bt = blockIdx.x;            // 0..511
    const int b = bt >> 7;
    const int tid = threadIdx.x;          // 0..255
    const int lane = tid & 63, wid = tid >> 6;
    const int len = lens[b];
    const int s0 = tid * 2;

    __shared__ float s_alpha[SS];
    __shared__ float s_red[8];

    // ---- phase A: partial scores for the two owned s positions ----
    float acc0 = 0.f, acc1 = 0.f;
    if (s0 < len) {
        const float2* qa = tqa + (size_t)bt * HD;
        const float* vp = vv;
        const ushort_t* col = (const ushort_t*)peT + (size_t)b * HD * SS + s0;
        #pragma unroll 4
        for (int h = 0; h < HD; h += 2) {
            uint_t pA = *(const uint_t*)(col + (size_t)h * SS);
            uint_t pB = *(const uint_t*)(col + (size_t)(h + 1) * SS);
            const float2 qA = qa[h], qB = qa[h + 1];
            const float vA = vp[h], vB = vp[h + 1];
            half2_t a01 = *(half2_t*)&pA;
            half2_t b01 = *(half2_t*)&pB;
            float teA0 = (float)a01[0], teA1 = (float)a01[1];
            float teB0 = (float)b01[0], teB1 = (float)b01[1];
            // s0
            float dA0 = fmaf(qA.x, teA0, 1.f);
            float dB0 = fmaf(qB.x, teB0, 1.f);
            float mA0 = fmaf(vA, teA0, qA.y);
            float mB0 = fmaf(vB, teB0, qB.y);
            float num0 = mA0 * dB0;
            num0 = fmaf(mB0, dA0, num0);
            acc0 = fmaf(num0, __builtin_amdgcn_rcpf(dA0 * dB0), acc0);
            // s0+1
            float dA1 = fmaf(qA.x, teA1, 1.f);
            float dB1 = fmaf(qB.x, teB1, 1.f);
            float mA1 = fmaf(vA, teA1, qA.y);
            float mB1 = fmaf(vB, teB1, qB.y);
            float num1 = mA1 * dB1;
            num1 = fmaf(mB1, dA1, num1);
            acc1 = fmaf(num1, __builtin_amdgcn_rcpf(dA1 * dB1), acc1);
        }
    }
    float sc0 = (s0     < len) ? acc0 : -INFINITY;
    float sc1 = (s0 + 1 < len) ? acc1 : -INFINITY;

    // ---- phase B: masked softmax over 512 s within the block ----
    float m = fmaxf(sc0, sc1);
    #pragma unroll
    for (int off = 32; off; off >>= 1) m = fmaxf(m, __shfl_xor(m, off, 64));
    if (lane == 0) s_red[wid] = m;
    __syncthreads();
    m = fmaxf(fmaxf(s_red[0], s_red[1]), fmaxf(s_red[2], s_red[3]));

    float e0 = __expf(sc0 - m);           // exp(-inf)=0 handles mask
    float e1 = __expf(sc1 - m);
    float sum = e0 + e1;
    #pragma unroll
    for (int off = 32; off; off >>= 1) sum += __shfl_xor(sum, off, 64);
    if (lane == 0) s_red[4 + wid] = sum;
    __syncthreads();
    float total = (s_red[4] + s_red[5]) + (s_red[6] + s_red[7]);
    float inv = __builtin_amdgcn_rcpf(total);
    s_alpha[s0]     = e0 * inv;
    s_alpha[s0 + 1] = e1 * inv;
    __syncthreads();

    // ---- phase C: out row = tanh(alpha @ encWo[b] + qWob[bt]) ----
    const int n0 = s0;                    // this thread owns cols n0, n0+1
    float2 qb = *(const float2*)(qWob + (size_t)bt * HD + n0);
    float p0a = qb.x, p0b = 0.f, p0c = 0.f, p0d = 0.f;
    float p1a = qb.y, p1b = 0.f, p1c = 0.f, p1d = 0.f;
    const ushort_t* ew = (const ushort_t*)encWo + (size_t)b * SS * HD + n0;
    const int lenR = (len + 3) & ~3;      // alpha is 0 past len
    for (int s = 0; s < lenR; s += 4) {
        uint_t w0 = *(const uint_t*)(ew + (size_t)(s + 0) * HD);
        uint_t w1 = *(const uint_t*)(ew + (size_t)(s + 1) * HD);
        uint_t w2 = *(const uint_t*)(ew + (size_t)(s + 2) * HD);
        uint_t w3 = *(const uint_t*)(ew + (size_t)(s + 3) * HD);
        float a0 = s_alpha[s], a1 = s_alpha[s + 1];
        float a2 = s_alpha[s + 2], a3 = s_alpha[s + 3];
        half2_t h0 = *(half2_t*)&w0, h1 = *(half2_t*)&w1;
        half2_t h2 = *(half2_t*)&w2, h3 = *(half2_t*)&w3;
        p0a = fmaf(a0, (float)h0[0], p0a); p1a = fmaf(a0, (float)h0[1], p1a);
        p0b = fmaf(a1, (float)h1[0], p0b); p1b = fmaf(a1, (float)h1[1], p1b);
        p0c = fmaf(a2, (float)h2[0], p0c); p1c = fmaf(a2, (float)h2[1], p1c);
        p0d = fmaf(a3, (float)h3[0], p0d); p1d = fmaf(a3, (float)h3[1], p1d);
    }
    float o0 = (p0a + p0b) + (p0c + p0d);
    float o1 = (p1a + p1b) + (p1c + p1d);
    float2 ov; ov.x = tanh_e(o0); ov.y = tanh_e(o1);
    *(float2*)(out + (size_t)bt * HD + n0) = ov;
}

extern "C" void kernel_launch(void* const* d_in, const int* in_sizes, int n_in,
                              void* d_out, int out_size, void* d_ws, size_t ws_size,
                              hipStream_t stream) {
    (void)in_sizes; (void)n_in; (void)out_size; (void)ws_size;
    const float* query = (const float*)d_in[0];   // (B,T,H)
    const float* enc   = (const float*)d_in[1];   // (B,S,H)
    const int*   lens  = (const int*)d_in[2];     // (B,)
    const float* W_h   = (const float*)d_in[3];   // (H,H)
    const float* W_s   = (const float*)d_in[4];   // (H,H)
    const float* v     = (const float*)d_in[5];   // (H,)
    const float* W_out = (const float*)d_in[6];   // (2H,H)
    float* out = (float*)d_out;

    // workspace layout (~12 MB)
    ushort_t* WTs   = (ushort_t*)d_ws;                          // 512 KB
    ushort_t* WTh   = WTs + (size_t)HD * HD;                    // 512 KB
    ushort_t* WTo   = WTh + (size_t)HD * HD;                    // 1 MB
    ushort_t* encB  = WTo + (size_t)HD * 2 * HD;                // 2 MB (bf16 enc)
    float2*   tqa   = (float2*)(encB + (size_t)BB * SS * HD);   // 2 MB {tanh(pq), v*tanh(pq)}
    _Float16* peT   = (_Float16*)(tqa + (size_t)BB * TT * HD);  // 2 MB fp16 tanh(pe)^T
    _Float16* encWo = peT + (size_t)BB * HD * SS;               // 2 MB fp16 enc@Wo_a
    float*    qWob  = (float*)(encWo + (size_t)BB * SS * HD);   // 1 MB fp32 q@Wo_b
    ushort_t* cq    = (ushort_t*)(qWob + (size_t)BB * TT * HD); // 1 MB (query bf16, right half)

    wtrans_kernel<<<dim3(768), 256, 0, stream>>>(W_s, W_h, W_out, query, enc,
                                                 WTs, WTh, WTo, cq, encB);
    proj_kernel<<<dim3(80, 8), 256, 0, stream>>>(cq, encB, WTs, WTh, WTo, v,
                                                 tqa, peT, encWo, qWob);
    fused_kernel<<<dim3(BB * TT), 256, 0, stream>>>(tqa, peT, v, encWo, qWob, lens, out);
}

// Round 2
// 129.183 us; speedup vs baseline: 1.1752x; 1.1752x over previous
//
#include <hip/hip_runtime.h>
#include <math.h>

#define HD 512
#define BB 4
#define TT 128
#define SS 512

typedef __attribute__((ext_vector_type(8))) short short8;
typedef __attribute__((ext_vector_type(4))) float floatx4;
typedef _Float16 half2_t __attribute__((ext_vector_type(2)));
typedef unsigned short ushort_t;
typedef unsigned int uint_t;

__device__ __forceinline__ float tanh_e(float x) {
    float t = __builtin_amdgcn_rcpf(__expf(2.f * x) + 1.f);
    return fmaf(-2.f, t, 1.f);
}
__device__ __forceinline__ ushort_t f2bf(float x) {      // RNE fp32->bf16
    unsigned int u = __float_as_uint(x);
    u += 0x7fffu + ((u >> 16) & 1u);
    return (ushort_t)(u >> 16);
}

// ---- Kernel 0: prep. W->bf16 [n][k] transposed (coalesced); query->cq right; enc->bf16 ----
// grid: 128 W-blocks (128k x 64n tiles) + 128 query blocks + 512 enc blocks = 768
__global__ __launch_bounds__(256) void wtrans_kernel(
    const float* __restrict__ Ws, const float* __restrict__ Wh,
    const float* __restrict__ Wo, const float* __restrict__ query,
    const float* __restrict__ enc,
    ushort_t* __restrict__ Ts, ushort_t* __restrict__ Th, ushort_t* __restrict__ To,
    ushort_t* __restrict__ cq, ushort_t* __restrict__ encB)
{
    const int bid = blockIdx.x;
    const int tid = threadIdx.x;
    if (bid < 128) {
        const float* src; ushort_t* dst; int K, l;
        if (bid < 32)      { src = Ws; dst = Ts; K = 512;  l = bid;      }
        else if (bid < 64) { src = Wh; dst = Th; K = 512;  l = bid - 32; }
        else               { src = Wo; dst = To; K = 1024; l = bid - 64; }
        const int ktiles = K >> 7;
        const int tk = l & (ktiles - 1), tn = l / ktiles;
        const int k0 = tk * 128, n0 = tn * 64;

        __shared__ ushort_t tile[64][136];     // [n][k], row 272B (16B aligned)

        const int lr  = tid >> 4;              // 0..15
        const int lc4 = (tid & 15) * 4;        // 0..60
        #pragma unroll
        for (int p = 0; p < 8; ++p) {
            const int row = p * 16 + lr;       // k-local
            float4 s = *(const float4*)(src + (size_t)(k0 + row) * HD + n0 + lc4);
            tile[lc4 + 0][row] = f2bf(s.x);
            tile[lc4 + 1][row] = f2bf(s.y);
            tile[lc4 + 2][row] = f2bf(s.z);
            tile[lc4 + 3][row] = f2bf(s.w);
        }
        __syncthreads();
        const int n = tid >> 2, kc = (tid & 3) * 32;
        #pragma unroll
        for (int j = 0; j < 4; ++j) {
            uint4 o = *(const uint4*)&tile[n][kc + j * 8];
            *(uint4*)&dst[(size_t)(n0 + n) * K + k0 + kc + j * 8] = o;
        }
    } else if (bid < 256) {
        // query -> bf16 into cq[m][512 + h]
        const int idx = ((bid - 128) * 256 + tid) * 8;
        const int m = idx >> 9, h = idx & 511;
        float4 q0 = *(const float4*)(query + (size_t)m * HD + h);
        float4 q1 = *(const float4*)(query + (size_t)m * HD + h + 4);
        uint4 o;
        o.x = (uint_t)f2bf(q0.x) | ((uint_t)f2bf(q0.y) << 16);
        o.y = (uint_t)f2bf(q0.z) | ((uint_t)f2bf(q0.w) << 16);
        o.z = (uint_t)f2bf(q1.x) | ((uint_t)f2bf(q1.y) << 16);
        o.w = (uint_t)f2bf(q1.z) | ((uint_t)f2bf(q1.w) << 16);
        *(uint4*)&cq[(size_t)m * 1024 + 512 + h] = o;
    } else {
        // enc -> bf16 encB (row-major)
        const size_t idx = ((size_t)(bid - 256) * 256 + tid) * 8;
        float4 e0 = *(const float4*)(enc + idx);
        float4 e1 = *(const float4*)(enc + idx + 4);
        uint4 o;
        o.x = (uint_t)f2bf(e0.x) | ((uint_t)f2bf(e0.y) << 16);
        o.y = (uint_t)f2bf(e0.z) | ((uint_t)f2bf(e0.w) << 16);
        o.z = (uint_t)f2bf(e1.x) | ((uint_t)f2bf(e1.y) << 16);
        o.w = (uint_t)f2bf(e1.z) | ((uint_t)f2bf(e1.w) << 16);
        *(uint4*)&encB[idx] = o;
    }
}

// ---- Kernel 1: MFMA proj, 4 GEMM families in one launch (grid 80 x 8):
//   bm  0..7 : tqa  = {tanh(q@Ws), v*tanh(q@Ws)}  fp32 pairs
//   bm 8..39 : peT  = fp16(tanh(enc@Wh))^T  (B,H,S)
//   bm 40..71: encWo= fp16(enc@Wo_a)        (B,S,H) row-major
//   bm 72..79: qWob = fp32(q@Wo_b)          (B*T,H)
#define LDP 40
__global__ __launch_bounds__(256) void proj_kernel(
    const ushort_t* __restrict__ cq, const ushort_t* __restrict__ encB,
    const ushort_t* __restrict__ WTs, const ushort_t* __restrict__ WTh,
    const ushort_t* __restrict__ WTo, const float* __restrict__ v,
    float2* __restrict__ tqa, _Float16* __restrict__ peT,
    _Float16* __restrict__ encWo, float* __restrict__ qWob)
{
    const int bm = blockIdx.x;            // 0..79
    const int bn = blockIdx.y;            // 0..7
    int type; const ushort_t* A; int lda; const ushort_t* B; int ldb; int m0;
    if (bm < 8)       { type = 0; A = cq + 512; lda = 1024; B = WTs;       ldb = 512;  m0 = bm * 64;        }
    else if (bm < 40) { type = 1; A = encB;     lda = 512;  B = WTh;       ldb = 512;  m0 = (bm - 8) * 64;  }
    else if (bm < 72) { type = 2; A = encB;     lda = 512;  B = WTo;       ldb = 1024; m0 = (bm - 40) * 64; }
    else              { type = 3; A = cq + 512; lda = 1024; B = WTo + 512; ldb = 1024; m0 = (bm - 72) * 64; }
    const int n0 = bn * 64;

    __shared__ ushort_t As[64 * LDP];     // [m][k]
    __shared__ ushort_t Bs[64 * LDP];     // [n][k]

    const int tid = threadIdx.x;
    const int lane = tid & 63, w = tid >> 6;
    const int quad = lane >> 4, lrow = lane & 15;
    const int mw = (w & 1) * 32, nw = (w >> 1) * 32;

    const int ar = tid >> 2;              // 0..63
    const int ac = (tid & 3) * 8;         // 0,8,16,24

    floatx4 zero = {0.f, 0.f, 0.f, 0.f};
    floatx4 acc[2][2] = {{zero, zero}, {zero, zero}};

    uint4 ald = *(const uint4*)&A[(size_t)(m0 + ar) * lda + ac];
    uint4 bld = *(const uint4*)&B[(size_t)(n0 + ar) * ldb + ac];

    for (int k0 = 0; k0 < HD; k0 += 32) {
        __syncthreads();
        *(uint4*)&As[ar * LDP + ac] = ald;
        *(uint4*)&Bs[ar * LDP + ac] = bld;
        __syncthreads();
        if (k0 + 32 < HD) {
            ald = *(const uint4*)&A[(size_t)(m0 + ar) * lda + k0 + 32 + ac];
            bld = *(const uint4*)&B[(size_t)(n0 + ar) * ldb + k0 + 32 + ac];
        }
        short8 af[2], bf[2];
        #pragma unroll
        for (int i = 0; i < 2; ++i)
            af[i] = *(const short8*)&As[(mw + i * 16 + lrow) * LDP + quad * 8];
        #pragma unroll
        for (int j = 0; j < 2; ++j)
            bf[j] = *(const short8*)&Bs[(nw + j * 16 + lrow) * LDP + quad * 8];
        #pragma unroll
        for (int i = 0; i < 2; ++i)
            #pragma unroll
            for (int j = 0; j < 2; ++j)
                acc[i][j] = __builtin_amdgcn_mfma_f32_16x16x32_bf16(af[i], bf[j], acc[i][j], 0, 0, 0);
    }

    if (type == 0) {
        #pragma unroll
        for (int j = 0; j < 2; ++j) {
            const int col = n0 + nw + j * 16 + lrow;
            const float vj = v[col];
            #pragma unroll
            for (int i = 0; i < 2; ++i)
                #pragma unroll
                for (int r = 0; r < 4; ++r) {
                    const int row = m0 + mw + i * 16 + quad * 4 + r;
                    float tq = tanh_e(acc[i][j][r]);
                    float2 o; o.x = tq; o.y = vj * tq;
                    tqa[(size_t)row * HD + col] = o;
                }
        }
    } else if (type == 1) {
        #pragma unroll
        for (int i = 0; i < 2; ++i)
            #pragma unroll
            for (int j = 0; j < 2; ++j) {
                const int gm = m0 + mw + i * 16 + quad * 4;
                const int b = gm >> 9, s = gm & 511;
                const int col = n0 + nw + j * 16 + lrow;
                _Float16 t0 = (_Float16)tanh_e(acc[i][j][0]);
                _Float16 t1 = (_Float16)tanh_e(acc[i][j][1]);
                _Float16 t2 = (_Float16)tanh_e(acc[i][j][2]);
                _Float16 t3 = (_Float16)tanh_e(acc[i][j][3]);
                ushort4 o;
                o.x = *(ushort_t*)&t0; o.y = *(ushort_t*)&t1;
                o.z = *(ushort_t*)&t2; o.w = *(ushort_t*)&t3;
                *(ushort4*)((ushort_t*)peT + ((size_t)b * HD + col) * SS + s) = o;
            }
    } else if (type == 2) {
        // encWo[b*S+s][n] fp16 row-major
        #pragma unroll
        for (int i = 0; i < 2; ++i)
            #pragma unroll
            for (int j = 0; j < 2; ++j) {
                const int col = n0 + nw + j * 16 + lrow;
                #pragma unroll
                for (int r = 0; r < 4; ++r) {
                    const int gm = m0 + mw + i * 16 + quad * 4 + r;
                    encWo[(size_t)gm * HD + col] = (_Float16)acc[i][j][r];
                }
            }
    } else {
        // qWob[b*T+t][n] fp32 (no activation)
        #pragma unroll
        for (int i = 0; i < 2; ++i)
            #pragma unroll
            for (int j = 0; j < 2; ++j) {
                const int col = n0 + nw + j * 16 + lrow;
                #pragma unroll
                for (int r = 0; r < 4; ++r) {
                    const int gm = m0 + mw + i * 16 + quad * 4 + r;
                    qWob[(size_t)gm * HD + col] = acc[i][j][r];
                }
            }
    }
}

// ---- Kernel 2: fused score + softmax + output row. One block (512 thr) per (b,t). ----
//  Two thread-halves split the reduction dim (h in phase A, s in phase C),
//  partials combined through LDS. tqa row + v staged in LDS (block-uniform).
__global__ __launch_bounds__(512) void fused_kernel(
    const float2* __restrict__ tqa, const _Float16* __restrict__ peT,
    const float* __restrict__ vv, const _Float16* __restrict__ encWo,
    const float* __restrict__ qWob, const int* __restrict__ lens,
    float* __restrict__ out)
{
    const int bt = blockIdx.x;            // 0..511
    const int b = bt >> 7;
    const int tid = threadIdx.x;          // 0..511
    const int lane = tid & 63, wid = tid >> 6;   // wid 0..7
    const int hh = tid >> 8;              // reduction-half: 0 or 1
    const int si = (tid & 255) * 2;       // owned s pair (phase A) / n pair (phase C)
    const int len = lens[b];

    __shared__ float2 s_q[HD];            // {tanh(pq), v*tanh(pq)} staged row (4KB)
    __shared__ float  s_v[HD];            // v (2KB)
    __shared__ float  s_sc[SS];           // partials / scores (2KB)
    __shared__ float  s_alpha[SS];        // softmax weights (2KB)
    __shared__ float  s_red[16];

    s_q[tid] = tqa[(size_t)bt * HD + tid];
    s_v[tid] = vv[tid];
    __syncthreads();

    // ---- phase A: half the h range per thread-half, 2 s per thread ----
    float acc0 = 0.f, acc1 = 0.f;
    if (si < len) {
        const ushort_t* col = (const ushort_t*)peT + (size_t)b * HD * SS + si;
        const int hbase = hh * 256;
        #pragma unroll 8
        for (int h = hbase; h < hbase + 256; h += 2) {
            uint_t pA = *(const uint_t*)(col + (size_t)h * SS);
            uint_t pB = *(const uint_t*)(col + (size_t)(h + 1) * SS);
            const float2 qA = s_q[h], qB = s_q[h + 1];
            const float vA = s_v[h], vB = s_v[h + 1];
            half2_t a01 = *(half2_t*)&pA;
            half2_t b01 = *(half2_t*)&pB;
            float teA0 = (float)a01[0], teA1 = (float)a01[1];
            float teB0 = (float)b01[0], teB1 = (float)b01[1];
            float dA0 = fmaf(qA.x, teA0, 1.f);
            float dB0 = fmaf(qB.x, teB0, 1.f);
            float mA0 = fmaf(vA, teA0, qA.y);
            float mB0 = fmaf(vB, teB0, qB.y);
            float num0 = mA0 * dB0;
            num0 = fmaf(mB0, dA0, num0);
            acc0 = fmaf(num0, __builtin_amdgcn_rcpf(dA0 * dB0), acc0);
            float dA1 = fmaf(qA.x, teA1, 1.f);
            float dB1 = fmaf(qB.x, teB1, 1.f);
            float mA1 = fmaf(vA, teA1, qA.y);
            float mB1 = fmaf(vB, teB1, qB.y);
            float num1 = mA1 * dB1;
            num1 = fmaf(mB1, dA1, num1);
            acc1 = fmaf(num1, __builtin_amdgcn_rcpf(dA1 * dB1), acc1);
        }
    }
    // combine the two h-halves through LDS
    if (hh) { s_sc[si] = acc0; s_sc[si + 1] = acc1; }
    __syncthreads();
    if (!hh) {
        float t0 = acc0 + s_sc[si], t1 = acc1 + s_sc[si + 1];
        s_sc[si]     = (si     < len) ? t0 : -INFINITY;
        s_sc[si + 1] = (si + 1 < len) ? t1 : -INFINITY;
    }
    __syncthreads();

    // ---- phase B: masked softmax over 512 s, 1 s per thread ----
    float sc = s_sc[tid];
    float m = sc;
    #pragma unroll
    for (int off = 32; off; off >>= 1) m = fmaxf(m, __shfl_xor(m, off, 64));
    if (lane == 0) s_red[wid] = m;
    __syncthreads();
    m = s_red[0];
    #pragma unroll
    for (int i2 = 1; i2 < 8; ++i2) m = fmaxf(m, s_red[i2]);

    float e = __expf(sc - m);             // exp(-inf)=0 handles mask
    float sum = e;
    #pragma unroll
    for (int off = 32; off; off >>= 1) sum += __shfl_xor(sum, off, 64);
    if (lane == 0) s_red[8 + wid] = sum;
    __syncthreads();
    float total = s_red[8];
    #pragma unroll
    for (int i2 = 1; i2 < 8; ++i2) total += s_red[8 + i2];
    s_alpha[tid] = e * __builtin_amdgcn_rcpf(total);
    __syncthreads();

    // ---- phase C: out[n0,n0+1] = tanh(alpha @ encWo[b] + qWob[bt]), s split in halves ----
    const int n0 = si;
    float p0a = 0.f, p0b = 0.f, p1a = 0.f, p1b = 0.f;
    const ushort_t* ew = (const ushort_t*)encWo + (size_t)b * SS * HD + n0;
    const int sbeg = hh * 256;
    const int lenR = (len + 1) & ~1;
    const int send = (sbeg + 256 < lenR) ? sbeg + 256 : lenR;  // alpha==0 past len
    #pragma unroll 8
    for (int s = sbeg; s < send; s += 2) {
        uint_t w0 = *(const uint_t*)(ew + (size_t)s * HD);
        uint_t w1 = *(const uint_t*)(ew + (size_t)(s + 1) * HD);
        float a0 = s_alpha[s], a1 = s_alpha[s + 1];
        half2_t h0 = *(half2_t*)&w0, h1 = *(half2_t*)&w1;
        p0a = fmaf(a0, (float)h0[0], p0a); p1a = fmaf(a0, (float)h0[1], p1a);
        p0b = fmaf(a1, (float)h1[0], p0b); p1b = fmaf(a1, (float)h1[1], p1b);
    }
    float p0 = p0a + p0b, p1 = p1a + p1b;
    if (hh) { s_sc[n0] = p0; s_sc[n0 + 1] = p1; }   // reuse s_sc for partials
    __syncthreads();
    if (!hh) {
        float2 qb = *(const float2*)(qWob + (size_t)bt * HD + n0);
        float o0 = p0 + s_sc[n0] + qb.x;
        float o1 = p1 + s_sc[n0 + 1] + qb.y;
        float2 ov; ov.x = tanh_e(o0); ov.y = tanh_e(o1);
        *(float2*)(out + (size_t)bt * HD + n0) = ov;
    }
}

extern "C" void kernel_launch(void* const* d_in, const int* in_sizes, int n_in,
                              void* d_out, int out_size, void* d_ws, size_t ws_size,
                              hipStream_t stream) {
    (void)in_sizes; (void)n_in; (void)out_size; (void)ws_size;
    const float* query = (const float*)d_in[0];   // (B,T,H)
    const float* enc   = (const float*)d_in[1];   // (B,S,H)
    const int*   lens  = (const int*)d_in[2];     // (B,)
    const float* W_h   = (const float*)d_in[3];   // (H,H)
    const float* W_s   = (const float*)d_in[4];   // (H,H)
    const float* v     = (const float*)d_in[5];   // (H,)
    const float* W_out = (const float*)d_in[6];   // (2H,H)
    float* out = (float*)d_out;

    // workspace layout (~12 MB)
    ushort_t* WTs   = (ushort_t*)d_ws;                          // 512 KB
    ushort_t* WTh   = WTs + (size_t)HD * HD;                    // 512 KB
    ushort_t* WTo   = WTh + (size_t)HD * HD;                    // 1 MB
    ushort_t* encB  = WTo + (size_t)HD * 2 * HD;                // 2 MB (bf16 enc)
    float2*   tqa   = (float2*)(encB + (size_t)BB * SS * HD);   // 2 MB {tanh(pq), v*tanh(pq)}
    _Float16* peT   = (_Float16*)(tqa + (size_t)BB * TT * HD);  // 2 MB fp16 tanh(pe)^T
    _Float16* encWo = peT + (size_t)BB * HD * SS;               // 2 MB fp16 enc@Wo_a
    float*    qWob  = (float*)(encWo + (size_t)BB * SS * HD);   // 1 MB fp32 q@Wo_b
    ushort_t* cq    = (ushort_t*)(qWob + (size_t)BB * TT * HD); // 1 MB (query bf16, right half)

    wtrans_kernel<<<dim3(768), 256, 0, stream>>>(W_s, W_h, W_out, query, enc,
                                                 WTs, WTh, WTo, cq, encB);
    proj_kernel<<<dim3(80, 8), 256, 0, stream>>>(cq, encB, WTs, WTh, WTo, v,
                                                 tqa, peT, encWo, qWob);
    fused_kernel<<<dim3(BB * TT), 512, 0, stream>>>(tqa, peT, v, encWo, qWob, lens, out);
}

// Round 3
// 118.629 us; speedup vs baseline: 1.2798x; 1.0890x over previous
//
#include <hip/hip_runtime.h>
#include <math.h>

#define HD 512
#define BB 4
#define TT 128
#define SS 512

typedef __attribute__((ext_vector_type(8))) short short8;
typedef __attribute__((ext_vector_type(4))) float floatx4;
typedef _Float16 half2_t __attribute__((ext_vector_type(2)));
typedef unsigned short ushort_t;
typedef unsigned int uint_t;

__device__ __forceinline__ float tanh_e(float x) {
    float t = __builtin_amdgcn_rcpf(__expf(2.f * x) + 1.f);
    return fmaf(-2.f, t, 1.f);
}
__device__ __forceinline__ ushort_t f2bf(float x) {      // RNE fp32->bf16
    unsigned int u = __float_as_uint(x);
    u += 0x7fffu + ((u >> 16) & 1u);
    return (ushort_t)(u >> 16);
}

// ---- Kernel 0: prep. W->bf16 [n][k] transposed (coalesced); query->cq right; enc->bf16 ----
// grid: 128 W-blocks (128k x 64n tiles) + 128 query blocks + 512 enc blocks = 768
__global__ __launch_bounds__(256) void wtrans_kernel(
    const float* __restrict__ Ws, const float* __restrict__ Wh,
    const float* __restrict__ Wo, const float* __restrict__ query,
    const float* __restrict__ enc,
    ushort_t* __restrict__ Ts, ushort_t* __restrict__ Th, ushort_t* __restrict__ To,
    ushort_t* __restrict__ cq, ushort_t* __restrict__ encB)
{
    const int bid = blockIdx.x;
    const int tid = threadIdx.x;
    if (bid < 128) {
        const float* src; ushort_t* dst; int K, l;
        if (bid < 32)      { src = Ws; dst = Ts; K = 512;  l = bid;      }
        else if (bid < 64) { src = Wh; dst = Th; K = 512;  l = bid - 32; }
        else               { src = Wo; dst = To; K = 1024; l = bid - 64; }
        const int ktiles = K >> 7;
        const int tk = l & (ktiles - 1), tn = l / ktiles;
        const int k0 = tk * 128, n0 = tn * 64;

        __shared__ ushort_t tile[64][136];     // [n][k], row 272B (16B aligned)

        const int lr  = tid >> 4;              // 0..15
        const int lc4 = (tid & 15) * 4;        // 0..60
        #pragma unroll
        for (int p = 0; p < 8; ++p) {
            const int row = p * 16 + lr;       // k-local
            float4 s = *(const float4*)(src + (size_t)(k0 + row) * HD + n0 + lc4);
            tile[lc4 + 0][row] = f2bf(s.x);
            tile[lc4 + 1][row] = f2bf(s.y);
            tile[lc4 + 2][row] = f2bf(s.z);
            tile[lc4 + 3][row] = f2bf(s.w);
        }
        __syncthreads();
        const int n = tid >> 2, kc = (tid & 3) * 32;
        #pragma unroll
        for (int j = 0; j < 4; ++j) {
            uint4 o = *(const uint4*)&tile[n][kc + j * 8];
            *(uint4*)&dst[(size_t)(n0 + n) * K + k0 + kc + j * 8] = o;
        }
    } else if (bid < 256) {
        // query -> bf16 into cq[m][512 + h]
        const int idx = ((bid - 128) * 256 + tid) * 8;
        const int m = idx >> 9, h = idx & 511;
        float4 q0 = *(const float4*)(query + (size_t)m * HD + h);
        float4 q1 = *(const float4*)(query + (size_t)m * HD + h + 4);
        uint4 o;
        o.x = (uint_t)f2bf(q0.x) | ((uint_t)f2bf(q0.y) << 16);
        o.y = (uint_t)f2bf(q0.z) | ((uint_t)f2bf(q0.w) << 16);
        o.z = (uint_t)f2bf(q1.x) | ((uint_t)f2bf(q1.y) << 16);
        o.w = (uint_t)f2bf(q1.z) | ((uint_t)f2bf(q1.w) << 16);
        *(uint4*)&cq[(size_t)m * 1024 + 512 + h] = o;
    } else {
        // enc -> bf16 encB (row-major)
        const size_t idx = ((size_t)(bid - 256) * 256 + tid) * 8;
        float4 e0 = *(const float4*)(enc + idx);
        float4 e1 = *(const float4*)(enc + idx + 4);
        uint4 o;
        o.x = (uint_t)f2bf(e0.x) | ((uint_t)f2bf(e0.y) << 16);
        o.y = (uint_t)f2bf(e0.z) | ((uint_t)f2bf(e0.w) << 16);
        o.z = (uint_t)f2bf(e1.x) | ((uint_t)f2bf(e1.y) << 16);
        o.w = (uint_t)f2bf(e1.z) | ((uint_t)f2bf(e1.w) << 16);
        *(uint4*)&encB[idx] = o;
    }
}

// ---- Kernel 1: MFMA proj, 4 GEMM families in one launch (grid 80 x 8):
//   bm  0..7 : tqa  = {tanh(q@Ws), v*tanh(q@Ws)}  fp32 pairs
//   bm 8..39 : peT  = fp16(tanh(enc@Wh))^T  (B,H,S)
//   bm 40..71: encWo= fp16(enc@Wo_a)        (B,S,H) row-major
//   bm 72..79: qWob = fp32(q@Wo_b)          (B*T,H)
#define LDP 40
__global__ __launch_bounds__(256) void proj_kernel(
    const ushort_t* __restrict__ cq, const ushort_t* __restrict__ encB,
    const ushort_t* __restrict__ WTs, const ushort_t* __restrict__ WTh,
    const ushort_t* __restrict__ WTo, const float* __restrict__ v,
    float2* __restrict__ tqa, _Float16* __restrict__ peT,
    _Float16* __restrict__ encWo, float* __restrict__ qWob)
{
    const int bm = blockIdx.x;            // 0..79
    const int bn = blockIdx.y;            // 0..7
    int type; const ushort_t* A; int lda; const ushort_t* B; int ldb; int m0;
    if (bm < 8)       { type = 0; A = cq + 512; lda = 1024; B = WTs;       ldb = 512;  m0 = bm * 64;        }
    else if (bm < 40) { type = 1; A = encB;     lda = 512;  B = WTh;       ldb = 512;  m0 = (bm - 8) * 64;  }
    else if (bm < 72) { type = 2; A = encB;     lda = 512;  B = WTo;       ldb = 1024; m0 = (bm - 40) * 64; }
    else              { type = 3; A = cq + 512; lda = 1024; B = WTo + 512; ldb = 1024; m0 = (bm - 72) * 64; }
    const int n0 = bn * 64;

    __shared__ ushort_t As[64 * LDP];     // [m][k]
    __shared__ ushort_t Bs[64 * LDP];     // [n][k]

    const int tid = threadIdx.x;
    const int lane = tid & 63, w = tid >> 6;
    const int quad = lane >> 4, lrow = lane & 15;
    const int mw = (w & 1) * 32, nw = (w >> 1) * 32;

    const int ar = tid >> 2;              // 0..63
    const int ac = (tid & 3) * 8;         // 0,8,16,24

    floatx4 zero = {0.f, 0.f, 0.f, 0.f};
    floatx4 acc[2][2] = {{zero, zero}, {zero, zero}};

    uint4 ald = *(const uint4*)&A[(size_t)(m0 + ar) * lda + ac];
    uint4 bld = *(const uint4*)&B[(size_t)(n0 + ar) * ldb + ac];

    for (int k0 = 0; k0 < HD; k0 += 32) {
        __syncthreads();
        *(uint4*)&As[ar * LDP + ac] = ald;
        *(uint4*)&Bs[ar * LDP + ac] = bld;
        __syncthreads();
        if (k0 + 32 < HD) {
            ald = *(const uint4*)&A[(size_t)(m0 + ar) * lda + k0 + 32 + ac];
            bld = *(const uint4*)&B[(size_t)(n0 + ar) * ldb + k0 + 32 + ac];
        }
        short8 af[2], bf[2];
        #pragma unroll
        for (int i = 0; i < 2; ++i)
            af[i] = *(const short8*)&As[(mw + i * 16 + lrow) * LDP + quad * 8];
        #pragma unroll
        for (int j = 0; j < 2; ++j)
            bf[j] = *(const short8*)&Bs[(nw + j * 16 + lrow) * LDP + quad * 8];
        #pragma unroll
        for (int i = 0; i < 2; ++i)
            #pragma unroll
            for (int j = 0; j < 2; ++j)
                acc[i][j] = __builtin_amdgcn_mfma_f32_16x16x32_bf16(af[i], bf[j], acc[i][j], 0, 0, 0);
    }

    if (type == 0) {
        #pragma unroll
        for (int j = 0; j < 2; ++j) {
            const int col = n0 + nw + j * 16 + lrow;
            const float vj = v[col];
            #pragma unroll
            for (int i = 0; i < 2; ++i)
                #pragma unroll
                for (int r = 0; r < 4; ++r) {
                    const int row = m0 + mw + i * 16 + quad * 4 + r;
                    float tq = tanh_e(acc[i][j][r]);
                    float2 o; o.x = tq; o.y = vj * tq;
                    tqa[(size_t)row * HD + col] = o;
                }
        }
    } else if (type == 1) {
        #pragma unroll
        for (int i = 0; i < 2; ++i)
            #pragma unroll
            for (int j = 0; j < 2; ++j) {
                const int gm = m0 + mw + i * 16 + quad * 4;
                const int b = gm >> 9, s = gm & 511;
                const int col = n0 + nw + j * 16 + lrow;
                _Float16 t0 = (_Float16)tanh_e(acc[i][j][0]);
                _Float16 t1 = (_Float16)tanh_e(acc[i][j][1]);
                _Float16 t2 = (_Float16)tanh_e(acc[i][j][2]);
                _Float16 t3 = (_Float16)tanh_e(acc[i][j][3]);
                ushort4 o;
                o.x = *(ushort_t*)&t0; o.y = *(ushort_t*)&t1;
                o.z = *(ushort_t*)&t2; o.w = *(ushort_t*)&t3;
                *(ushort4*)((ushort_t*)peT + ((size_t)b * HD + col) * SS + s) = o;
            }
    } else if (type == 2) {
        // encWo[b*S+s][n] fp16 row-major
        #pragma unroll
        for (int i = 0; i < 2; ++i)
            #pragma unroll
            for (int j = 0; j < 2; ++j) {
                const int col = n0 + nw + j * 16 + lrow;
                #pragma unroll
                for (int r = 0; r < 4; ++r) {
                    const int gm = m0 + mw + i * 16 + quad * 4 + r;
                    encWo[(size_t)gm * HD + col] = (_Float16)acc[i][j][r];
                }
            }
    } else {
        // qWob[b*T+t][n] fp32 (no activation)
        #pragma unroll
        for (int i = 0; i < 2; ++i)
            #pragma unroll
            for (int j = 0; j < 2; ++j) {
                const int col = n0 + nw + j * 16 + lrow;
                #pragma unroll
                for (int r = 0; r < 4; ++r) {
                    const int gm = m0 + mw + i * 16 + quad * 4 + r;
                    qWob[(size_t)gm * HD + col] = acc[i][j][r];
                }
            }
    }
}

// ---- Kernel 2: fused score + softmax + output row. One block (512 thr) per (b,t). ----
//  Packed-fp16 math: each thread's two s (phase A) / two n (phase C) live in the
//  halves of a half2 -> v_pk_*_f16. Block-uniform per-h values pre-broadcast in a
//  uint4 LDS table (1 ds_read_b128 broadcast per h). rcp + accumulation stay f32.
__global__ __launch_bounds__(512) void fused_kernel(
    const float2* __restrict__ tqa, const _Float16* __restrict__ peT,
    const float* __restrict__ vv, const _Float16* __restrict__ encWo,
    const float* __restrict__ qWob, const int* __restrict__ lens,
    float* __restrict__ out)
{
    const int bt = blockIdx.x;            // 0..511
    const int b = bt >> 7;
    const int tid = threadIdx.x;          // 0..511
    const int lane = tid & 63, wid = tid >> 6;   // wid 0..7
    const int hh = tid >> 8;              // reduction-half: 0 or 1
    const int si = (tid & 255) * 2;       // owned s pair (phase A) / n pair (phase C)
    const int len = lens[b];

    __shared__ uint4  s_tab[HD];          // 8 KB: {Tq2, v2, vTq2, -} fp16 broadcast pairs
    __shared__ float  s_sc[SS];           // 2 KB: partials / scores
    __shared__ uint_t s_al2[SS];          // 2 KB: fp16 alpha broadcast pairs
    __shared__ float  s_red[16];

    // build broadcast table: one h per thread
    {
        float2 q = tqa[(size_t)bt * HD + tid];
        float vh = vv[tid];
        _Float16 tqh = (_Float16)q.x, vvh = (_Float16)vh, vth = (_Float16)q.y;
        uint_t ta = *(ushort_t*)&tqh, tb = *(ushort_t*)&vvh, tc = *(ushort_t*)&vth;
        uint4 e; e.x = ta | (ta << 16); e.y = tb | (tb << 16); e.z = tc | (tc << 16); e.w = 0;
        s_tab[tid] = e;
    }
    __syncthreads();

    // ---- phase A: half the h range per thread-half, 2 s packed in half2 ----
    float acc0 = 0.f, acc1 = 0.f;
    if (si < len) {
        const ushort_t* colp = (const ushort_t*)peT + (size_t)b * HD * SS
                             + (size_t)(hh * 256) * SS + si;
        const uint4* tabp = &s_tab[hh * 256];
        half2_t one2; one2[0] = (_Float16)1.f; one2[1] = (_Float16)1.f;
        #pragma unroll 4
        for (int hp = 0; hp < 128; ++hp) {
            uint_t pA = *(const uint_t*)(colp + (size_t)(2 * hp) * SS);
            uint_t pB = *(const uint_t*)(colp + (size_t)(2 * hp + 1) * SS);
            uint4 cA = tabp[2 * hp], cB = tabp[2 * hp + 1];
            half2_t teA = *(half2_t*)&pA, teB = *(half2_t*)&pB;
            half2_t tqA = *(half2_t*)&cA.x, vA = *(half2_t*)&cA.y, vtA = *(half2_t*)&cA.z;
            half2_t tqB = *(half2_t*)&cB.x, vB = *(half2_t*)&cB.y, vtB = *(half2_t*)&cB.z;
            half2_t dA = tqA * teA + one2;            // 1 + Tq*Te   (pk_fma)
            half2_t dB = tqB * teB + one2;
            half2_t mA = vA * teA + vtA;              // v*Te + v*Tq (pk_fma)
            half2_t mB = vB * teB + vtB;
            half2_t num = mA * dB + mB * dA;          // pk_mul + pk_fma
            half2_t den = dA * dB;                    // pk_mul
            float nf0 = (float)num[0], nf1 = (float)num[1];
            float df0 = (float)den[0], df1 = (float)den[1];
            acc0 = fmaf(nf0, __builtin_amdgcn_rcpf(df0), acc0);
            acc1 = fmaf(nf1, __builtin_amdgcn_rcpf(df1), acc1);
        }
    }
    // combine the two h-halves through LDS
    if (hh) { s_sc[si] = acc0; s_sc[si + 1] = acc1; }
    __syncthreads();
    if (!hh) {
        float t0 = acc0 + s_sc[si], t1 = acc1 + s_sc[si + 1];
        s_sc[si]     = (si     < len) ? t0 : -INFINITY;
        s_sc[si + 1] = (si + 1 < len) ? t1 : -INFINITY;
    }
    __syncthreads();

    // ---- phase B: masked softmax over 512 s, 1 s per thread ----
    float sc = s_sc[tid];
    float m = sc;
    #pragma unroll
    for (int off = 32; off; off >>= 1) m = fmaxf(m, __shfl_xor(m, off, 64));
    if (lane == 0) s_red[wid] = m;
    __syncthreads();
    m = s_red[0];
    #pragma unroll
    for (int i2 = 1; i2 < 8; ++i2) m = fmaxf(m, s_red[i2]);

    float e = __expf(sc - m);             // exp(-inf)=0 handles mask
    float sum = e;
    #pragma unroll
    for (int off = 32; off; off >>= 1) sum += __shfl_xor(sum, off, 64);
    if (lane == 0) s_red[8 + wid] = sum;
    __syncthreads();
    float total = s_red[8];
    #pragma unroll
    for (int i2 = 1; i2 < 8; ++i2) total += s_red[8 + i2];
    {
        float a = e * __builtin_amdgcn_rcpf(total);
        _Float16 ah = (_Float16)a;
        uint_t ap = *(ushort_t*)&ah;
        s_al2[tid] = ap | (ap << 16);     // broadcast pair; ==0 past len
    }
    __syncthreads();

    // ---- phase C: out[n0,n0+1] = tanh(alpha @ encWo[b] + qWob[bt]), s split in halves ----
    const int n0 = si;
    float o0 = 0.f, o1 = 0.f;
    const ushort_t* ew = (const ushort_t*)encWo + (size_t)b * SS * HD + n0;
    const int sbeg = hh * 256;
    const int send = (sbeg + 256 < len) ? sbeg + 256 : len;   // alpha==0 past len
    int s = sbeg;
    for (; s + 16 <= send; s += 16) {
        half2_t acch; acch[0] = (_Float16)0.f; acch[1] = (_Float16)0.f;
        #pragma unroll
        for (int k = 0; k < 16; ++k) {
            uint_t wv = *(const uint_t*)(ew + (size_t)(s + k) * HD);
            uint_t av = s_al2[s + k];
            half2_t eh = *(half2_t*)&wv, a2 = *(half2_t*)&av;
            acch = a2 * eh + acch;        // pk_fma
        }
        o0 += (float)acch[0]; o1 += (float)acch[1];   // f32 flush per 16 s
    }
    for (; s < send; ++s) {               // tail < 16
        uint_t wv = *(const uint_t*)(ew + (size_t)s * HD);
        half2_t eh = *(half2_t*)&wv;
        uint_t av = s_al2[s];
        _Float16 ah16 = *(_Float16*)&av;
        float a = (float)ah16;
        o0 = fmaf(a, (float)eh[0], o0);
        o1 = fmaf(a, (float)eh[1], o1);
    }
    if (hh) { s_sc[n0] = o0; s_sc[n0 + 1] = o1; }   // reuse s_sc for partials
    __syncthreads();
    if (!hh) {
        float2 qb = *(const float2*)(qWob + (size_t)bt * HD + n0);
        float f0 = o0 + s_sc[n0] + qb.x;
        float f1 = o1 + s_sc[n0 + 1] + qb.y;
        float2 ov; ov.x = tanh_e(f0); ov.y = tanh_e(f1);
        *(float2*)(out + (size_t)bt * HD + n0) = ov;
    }
}

extern "C" void kernel_launch(void* const* d_in, const int* in_sizes, int n_in,
                              void* d_out, int out_size, void* d_ws, size_t ws_size,
                              hipStream_t stream) {
    (void)in_sizes; (void)n_in; (void)out_size; (void)ws_size;
    const float* query = (const float*)d_in[0];   // (B,T,H)
    const float* enc   = (const float*)d_in[1];   // (B,S,H)
    const int*   lens  = (const int*)d_in[2];     // (B,)
    const float* W_h   = (const float*)d_in[3];   // (H,H)
    const float* W_s   = (const float*)d_in[4];   // (H,H)
    const float* v     = (const float*)d_in[5];   // (H,)
    const float* W_out = (const float*)d_in[6];   // (2H,H)
    float* out = (float*)d_out;

    // workspace layout (~12 MB)
    ushort_t* WTs   = (ushort_t*)d_ws;                          // 512 KB
    ushort_t* WTh   = WTs + (size_t)HD * HD;                    // 512 KB
    ushort_t* WTo   = WTh + (size_t)HD * HD;                    // 1 MB
    ushort_t* encB  = WTo + (size_t)HD * 2 * HD;                // 2 MB (bf16 enc)
    float2*   tqa   = (float2*)(encB + (size_t)BB * SS * HD);   // 2 MB {tanh(pq), v*tanh(pq)}
    _Float16* peT   = (_Float16*)(tqa + (size_t)BB * TT * HD);  // 2 MB fp16 tanh(pe)^T
    _Float16* encWo = peT + (size_t)BB * HD * SS;               // 2 MB fp16 enc@Wo_a
    float*    qWob  = (float*)(encWo + (size_t)BB * SS * HD);   // 1 MB fp32 q@Wo_b
    ushort_t* cq    = (ushort_t*)(qWob + (size_t)BB * TT * HD); // 1 MB (query bf16, right half)

    wtrans_kernel<<<dim3(768), 256, 0, stream>>>(W_s, W_h, W_out, query, enc,
                                                 WTs, WTh, WTo, cq, encB);
    proj_kernel<<<dim3(80, 8), 256, 0, stream>>>(cq, encB, WTs, WTh, WTo, v,
                                                 tqa, peT, encWo, qWob);
    fused_kernel<<<dim3(BB * TT), 512, 0, stream>>>(tqa, peT, v, encWo, qWob, lens, out);
}

// Round 4
// 118.185 us; speedup vs baseline: 1.2846x; 1.0038x over previous
//
#include <hip/hip_runtime.h>
#include <math.h>

#define HD 512
#define BB 4
#define TT 128
#define SS 512

typedef __attribute__((ext_vector_type(8))) short short8;
typedef __attribute__((ext_vector_type(4))) float floatx4;
typedef _Float16 half2_t __attribute__((ext_vector_type(2)));
typedef unsigned short ushort_t;
typedef unsigned int uint_t;

__device__ __forceinline__ float tanh_e(float x) {
    float t = __builtin_amdgcn_rcpf(__expf(2.f * x) + 1.f);
    return fmaf(-2.f, t, 1.f);
}
__device__ __forceinline__ ushort_t f2bf(float x) {      // RNE fp32->bf16
    unsigned int u = __float_as_uint(x);
    u += 0x7fffu + ((u >> 16) & 1u);
    return (ushort_t)(u >> 16);
}

// ---- Kernel 0: prep. W->bf16 [n][k] transposed (coalesced); query->cq right; enc->bf16 ----
// grid: 128 W-blocks (128k x 64n tiles) + 128 query blocks + 512 enc blocks = 768
__global__ __launch_bounds__(256) void wtrans_kernel(
    const float* __restrict__ Ws, const float* __restrict__ Wh,
    const float* __restrict__ Wo, const float* __restrict__ query,
    const float* __restrict__ enc,
    ushort_t* __restrict__ Ts, ushort_t* __restrict__ Th, ushort_t* __restrict__ To,
    ushort_t* __restrict__ cq, ushort_t* __restrict__ encB)
{
    const int bid = blockIdx.x;
    const int tid = threadIdx.x;
    if (bid < 128) {
        const float* src; ushort_t* dst; int K, l;
        if (bid < 32)      { src = Ws; dst = Ts; K = 512;  l = bid;      }
        else if (bid < 64) { src = Wh; dst = Th; K = 512;  l = bid - 32; }
        else               { src = Wo; dst = To; K = 1024; l = bid - 64; }
        const int ktiles = K >> 7;
        const int tk = l & (ktiles - 1), tn = l / ktiles;
        const int k0 = tk * 128, n0 = tn * 64;

        __shared__ ushort_t tile[64][136];     // [n][k], row 272B (16B aligned)

        const int lr  = tid >> 4;              // 0..15
        const int lc4 = (tid & 15) * 4;        // 0..60
        #pragma unroll
        for (int p = 0; p < 8; ++p) {
            const int row = p * 16 + lr;       // k-local
            float4 s = *(const float4*)(src + (size_t)(k0 + row) * HD + n0 + lc4);
            tile[lc4 + 0][row] = f2bf(s.x);
            tile[lc4 + 1][row] = f2bf(s.y);
            tile[lc4 + 2][row] = f2bf(s.z);
            tile[lc4 + 3][row] = f2bf(s.w);
        }
        __syncthreads();
        const int n = tid >> 2, kc = (tid & 3) * 32;
        #pragma unroll
        for (int j = 0; j < 4; ++j) {
            uint4 o = *(const uint4*)&tile[n][kc + j * 8];
            *(uint4*)&dst[(size_t)(n0 + n) * K + k0 + kc + j * 8] = o;
        }
    } else if (bid < 256) {
        // query -> bf16 into cq[m][512 + h]
        const int idx = ((bid - 128) * 256 + tid) * 8;
        const int m = idx >> 9, h = idx & 511;
        float4 q0 = *(const float4*)(query + (size_t)m * HD + h);
        float4 q1 = *(const float4*)(query + (size_t)m * HD + h + 4);
        uint4 o;
        o.x = (uint_t)f2bf(q0.x) | ((uint_t)f2bf(q0.y) << 16);
        o.y = (uint_t)f2bf(q0.z) | ((uint_t)f2bf(q0.w) << 16);
        o.z = (uint_t)f2bf(q1.x) | ((uint_t)f2bf(q1.y) << 16);
        o.w = (uint_t)f2bf(q1.z) | ((uint_t)f2bf(q1.w) << 16);
        *(uint4*)&cq[(size_t)m * 1024 + 512 + h] = o;
    } else {
        // enc -> bf16 encB (row-major)
        const size_t idx = ((size_t)(bid - 256) * 256 + tid) * 8;
        float4 e0 = *(const float4*)(enc + idx);
        float4 e1 = *(const float4*)(enc + idx + 4);
        uint4 o;
        o.x = (uint_t)f2bf(e0.x) | ((uint_t)f2bf(e0.y) << 16);
        o.y = (uint_t)f2bf(e0.z) | ((uint_t)f2bf(e0.w) << 16);
        o.z = (uint_t)f2bf(e1.x) | ((uint_t)f2bf(e1.y) << 16);
        o.w = (uint_t)f2bf(e1.z) | ((uint_t)f2bf(e1.w) << 16);
        *(uint4*)&encB[idx] = o;
    }
}

// ---- Kernel 1: MFMA proj, 4 GEMM families in one launch (grid 80 x 8):
//   bm  0..7 : tqa  = {tanh(q@Ws), v*tanh(q@Ws)}  fp32 pairs
//   bm 8..39 : peT  = fp16(tanh(enc@Wh))^T  (B,H,S)
//   bm 40..71: encWo= fp16(enc@Wo_a)        (B,S,H) row-major
//   bm 72..79: qWob = fp32(q@Wo_b)          (B*T,H)
#define LDP 40
__global__ __launch_bounds__(256) void proj_kernel(
    const ushort_t* __restrict__ cq, const ushort_t* __restrict__ encB,
    const ushort_t* __restrict__ WTs, const ushort_t* __restrict__ WTh,
    const ushort_t* __restrict__ WTo, const float* __restrict__ v,
    float2* __restrict__ tqa, _Float16* __restrict__ peT,
    _Float16* __restrict__ encWo, float* __restrict__ qWob)
{
    const int bm = blockIdx.x;            // 0..79
    const int bn = blockIdx.y;            // 0..7
    int type; const ushort_t* A; int lda; const ushort_t* B; int ldb; int m0;
    if (bm < 8)       { type = 0; A = cq + 512; lda = 1024; B = WTs;       ldb = 512;  m0 = bm * 64;        }
    else if (bm < 40) { type = 1; A = encB;     lda = 512;  B = WTh;       ldb = 512;  m0 = (bm - 8) * 64;  }
    else if (bm < 72) { type = 2; A = encB;     lda = 512;  B = WTo;       ldb = 1024; m0 = (bm - 40) * 64; }
    else              { type = 3; A = cq + 512; lda = 1024; B = WTo + 512; ldb = 1024; m0 = (bm - 72) * 64; }
    const int n0 = bn * 64;

    __shared__ ushort_t As[64 * LDP];     // [m][k]
    __shared__ ushort_t Bs[64 * LDP];     // [n][k]

    const int tid = threadIdx.x;
    const int lane = tid & 63, w = tid >> 6;
    const int quad = lane >> 4, lrow = lane & 15;
    const int mw = (w & 1) * 32, nw = (w >> 1) * 32;

    const int ar = tid >> 2;              // 0..63
    const int ac = (tid & 3) * 8;         // 0,8,16,24

    floatx4 zero = {0.f, 0.f, 0.f, 0.f};
    floatx4 acc[2][2] = {{zero, zero}, {zero, zero}};

    uint4 ald = *(const uint4*)&A[(size_t)(m0 + ar) * lda + ac];
    uint4 bld = *(const uint4*)&B[(size_t)(n0 + ar) * ldb + ac];

    for (int k0 = 0; k0 < HD; k0 += 32) {
        __syncthreads();
        *(uint4*)&As[ar * LDP + ac] = ald;
        *(uint4*)&Bs[ar * LDP + ac] = bld;
        __syncthreads();
        if (k0 + 32 < HD) {
            ald = *(const uint4*)&A[(size_t)(m0 + ar) * lda + k0 + 32 + ac];
            bld = *(const uint4*)&B[(size_t)(n0 + ar) * ldb + k0 + 32 + ac];
        }
        short8 af[2], bf[2];
        #pragma unroll
        for (int i = 0; i < 2; ++i)
            af[i] = *(const short8*)&As[(mw + i * 16 + lrow) * LDP + quad * 8];
        #pragma unroll
        for (int j = 0; j < 2; ++j)
            bf[j] = *(const short8*)&Bs[(nw + j * 16 + lrow) * LDP + quad * 8];
        #pragma unroll
        for (int i = 0; i < 2; ++i)
            #pragma unroll
            for (int j = 0; j < 2; ++j)
                acc[i][j] = __builtin_amdgcn_mfma_f32_16x16x32_bf16(af[i], bf[j], acc[i][j], 0, 0, 0);
    }

    if (type == 0) {
        #pragma unroll
        for (int j = 0; j < 2; ++j) {
            const int col = n0 + nw + j * 16 + lrow;
            const float vj = v[col];
            #pragma unroll
            for (int i = 0; i < 2; ++i)
                #pragma unroll
                for (int r = 0; r < 4; ++r) {
                    const int row = m0 + mw + i * 16 + quad * 4 + r;
                    float tq = tanh_e(acc[i][j][r]);
                    float2 o; o.x = tq; o.y = vj * tq;
                    tqa[(size_t)row * HD + col] = o;
                }
        }
    } else if (type == 1) {
        #pragma unroll
        for (int i = 0; i < 2; ++i)
            #pragma unroll
            for (int j = 0; j < 2; ++j) {
                const int gm = m0 + mw + i * 16 + quad * 4;
                const int b = gm >> 9, s = gm & 511;
                const int col = n0 + nw + j * 16 + lrow;
                _Float16 t0 = (_Float16)tanh_e(acc[i][j][0]);
                _Float16 t1 = (_Float16)tanh_e(acc[i][j][1]);
                _Float16 t2 = (_Float16)tanh_e(acc[i][j][2]);
                _Float16 t3 = (_Float16)tanh_e(acc[i][j][3]);
                ushort4 o;
                o.x = *(ushort_t*)&t0; o.y = *(ushort_t*)&t1;
                o.z = *(ushort_t*)&t2; o.w = *(ushort_t*)&t3;
                *(ushort4*)((ushort_t*)peT + ((size_t)b * HD + col) * SS + s) = o;
            }
    } else if (type == 2) {
        // encWo[b*S+s][n] fp16 row-major
        #pragma unroll
        for (int i = 0; i < 2; ++i)
            #pragma unroll
            for (int j = 0; j < 2; ++j) {
                const int col = n0 + nw + j * 16 + lrow;
                #pragma unroll
                for (int r = 0; r < 4; ++r) {
                    const int gm = m0 + mw + i * 16 + quad * 4 + r;
                    encWo[(size_t)gm * HD + col] = (_Float16)acc[i][j][r];
                }
            }
    } else {
        // qWob[b*T+t][n] fp32 (no activation)
        #pragma unroll
        for (int i = 0; i < 2; ++i)
            #pragma unroll
            for (int j = 0; j < 2; ++j) {
                const int col = n0 + nw + j * 16 + lrow;
                #pragma unroll
                for (int r = 0; r < 4; ++r) {
                    const int gm = m0 + mw + i * 16 + quad * 4 + r;
                    qWob[(size_t)gm * HD + col] = acc[i][j][r];
                }
            }
    }
}

// ---- Kernel 2: fused score + softmax + output row. One block (1024 thr) per (b,t). ----
//  Phase A: thread = (4 s, 1/8 of h). Phase C: thread = (4 n, 1/8 of s).
//  8-way reduction-partials combined through LDS. Packed-fp16 math throughout;
//  rcp + final accumulation in f32. launch_bounds(1024,8) -> VGPR<=64, 2 blk/CU.
__global__ __launch_bounds__(1024, 8) void fused_kernel(
    const float2* __restrict__ tqa, const _Float16* __restrict__ peT,
    const float* __restrict__ vv, const _Float16* __restrict__ encWo,
    const float* __restrict__ qWob, const int* __restrict__ lens,
    float* __restrict__ out)
{
    const int bt = blockIdx.x;            // 0..511
    const int b = bt >> 7;
    const int tid = threadIdx.x;          // 0..1023
    const int lane = tid & 63, wid = tid >> 6;   // wid 0..15
    const int len = lens[b];

    __shared__ uint4  s_tab[HD];          // 8 KB: {Tq2, v2, vTq2, -} fp16 broadcast pairs
    __shared__ float  s_part[7 * SS];     // 14 KB: 8-way reduction partials (A and C)
    __shared__ float  s_sc[SS];           // 2 KB: scores
    __shared__ uint_t s_al2[SS];          // 2 KB: fp16 alpha broadcast pairs
    __shared__ float  s_red[32];

    // build broadcast table: one h per thread (tid<512)
    if (tid < HD) {
        float2 q = tqa[(size_t)bt * HD + tid];
        float vh = vv[tid];
        _Float16 tqh = (_Float16)q.x, vvh = (_Float16)vh, vth = (_Float16)q.y;
        uint_t ta = *(ushort_t*)&tqh, tb = *(ushort_t*)&vvh, tc = *(ushort_t*)&vth;
        uint4 e4; e4.x = ta | (ta << 16); e4.y = tb | (tb << 16); e4.z = tc | (tc << 16); e4.w = 0;
        s_tab[tid] = e4;
    }
    __syncthreads();

    // ---- phase A: 4 s per thread (dwordx2/h-row), 1/8 of h; 2h pair-combined ----
    const int sg = tid & 127, hq = tid >> 7;     // hq wave-uniform
    const int s0 = sg * 4;
    const int hbase = hq * 64;
    float a0 = 0.f, a1 = 0.f, a2 = 0.f, a3 = 0.f;
    if (s0 < len) {
        const ushort_t* colp = (const ushort_t*)peT + ((size_t)b * HD + hbase) * SS + s0;
        const uint4* tabp = &s_tab[hbase];
        half2_t one2; one2[0] = (_Float16)1.f; one2[1] = (_Float16)1.f;
        #pragma unroll 2
        for (int i = 0; i < 32; ++i) {
            uint2 pA = *(const uint2*)(colp);
            uint2 pB = *(const uint2*)(colp + SS);
            colp += 2 * SS;
            uint4 cA = tabp[2 * i], cB = tabp[2 * i + 1];
            half2_t tqA = *(half2_t*)&cA.x, vA = *(half2_t*)&cA.y, vtA = *(half2_t*)&cA.z;
            half2_t tqB = *(half2_t*)&cB.x, vB = *(half2_t*)&cB.y, vtB = *(half2_t*)&cB.z;
            half2_t teA01 = *(half2_t*)&pA.x, teA23 = *(half2_t*)&pA.y;
            half2_t teB01 = *(half2_t*)&pB.x, teB23 = *(half2_t*)&pB.y;
            half2_t dA01 = tqA * teA01 + one2, dA23 = tqA * teA23 + one2;
            half2_t dB01 = tqB * teB01 + one2, dB23 = tqB * teB23 + one2;
            half2_t mA01 = vA * teA01 + vtA,  mA23 = vA * teA23 + vtA;
            half2_t mB01 = vB * teB01 + vtB,  mB23 = vB * teB23 + vtB;
            half2_t n01 = mA01 * dB01 + mB01 * dA01;
            half2_t n23 = mA23 * dB23 + mB23 * dA23;
            half2_t d01 = dA01 * dB01, d23 = dA23 * dB23;
            a0 = fmaf((float)n01[0], __builtin_amdgcn_rcpf((float)d01[0]), a0);
            a1 = fmaf((float)n01[1], __builtin_amdgcn_rcpf((float)d01[1]), a1);
            a2 = fmaf((float)n23[0], __builtin_amdgcn_rcpf((float)d23[0]), a2);
            a3 = fmaf((float)n23[1], __builtin_amdgcn_rcpf((float)d23[1]), a3);
        }
    }
    if (hq) {
        float4 p; p.x = a0; p.y = a1; p.z = a2; p.w = a3;
        *(float4*)&s_part[(hq - 1) * SS + s0] = p;
    }
    __syncthreads();
    if (!hq) {
        float t0 = a0, t1 = a1, t2 = a2, t3 = a3;
        #pragma unroll
        for (int q = 0; q < 7; ++q) {
            float4 p = *(const float4*)&s_part[q * SS + s0];
            t0 += p.x; t1 += p.y; t2 += p.z; t3 += p.w;
        }
        s_sc[s0]     = (s0     < len) ? t0 : -INFINITY;
        s_sc[s0 + 1] = (s0 + 1 < len) ? t1 : -INFINITY;
        s_sc[s0 + 2] = (s0 + 2 < len) ? t2 : -INFINITY;
        s_sc[s0 + 3] = (s0 + 3 < len) ? t3 : -INFINITY;
    }
    __syncthreads();

    // ---- phase B: masked softmax over 512 s (threads 0..511 own 1 s each) ----
    float sc = (tid < SS) ? s_sc[tid] : -INFINITY;
    float m = sc;
    #pragma unroll
    for (int off = 32; off; off >>= 1) m = fmaxf(m, __shfl_xor(m, off, 64));
    if (lane == 0) s_red[wid] = m;
    __syncthreads();
    m = s_red[0];
    #pragma unroll
    for (int i2 = 1; i2 < 16; ++i2) m = fmaxf(m, s_red[i2]);

    float e = (tid < SS) ? __expf(sc - m) : 0.f;
    float sum = e;
    #pragma unroll
    for (int off = 32; off; off >>= 1) sum += __shfl_xor(sum, off, 64);
    if (lane == 0) s_red[16 + wid] = sum;
    __syncthreads();
    float total = s_red[16];
    #pragma unroll
    for (int i2 = 1; i2 < 16; ++i2) total += s_red[16 + i2];
    if (tid < SS) {
        float a = e * __builtin_amdgcn_rcpf(total);
        _Float16 ah = (_Float16)a;
        uint_t ap = *(ushort_t*)&ah;
        s_al2[tid] = ap | (ap << 16);     // broadcast pair; ==0 past len
    }
    __syncthreads();

    // ---- phase C: 4 n per thread (dwordx2/s-row), 1/8 of s; fp16 chunk accum ----
    const int ng = tid & 127, sq = tid >> 7;     // sq wave-uniform
    const int n0 = ng * 4;
    const int sbeg = sq * 64;
    float o0 = 0.f, o1 = 0.f, o2 = 0.f, o3 = 0.f;
    {
        const ushort_t* ew = (const ushort_t*)encWo + ((size_t)b * SS + sbeg) * HD + n0;
        const int rem = (len > sbeg) ? ((len - sbeg < 64) ? len - sbeg : 64) : 0;
        const int schunks = (rem + 7) >> 3;      // alpha==0 past len -> full chunks safe
        for (int c = 0; c < schunks; ++c) {
            half2_t acc01; acc01[0] = (_Float16)0.f; acc01[1] = (_Float16)0.f;
            half2_t acc23; acc23[0] = (_Float16)0.f; acc23[1] = (_Float16)0.f;
            const ushort_t* ewc = ew + (size_t)(c * 8) * HD;
            #pragma unroll
            for (int k = 0; k < 8; ++k) {
                uint2 wv = *(const uint2*)(ewc + (size_t)k * HD);
                uint_t av = s_al2[sbeg + c * 8 + k];
                half2_t a2h = *(half2_t*)&av;
                acc01 = a2h * (*(half2_t*)&wv.x) + acc01;
                acc23 = a2h * (*(half2_t*)&wv.y) + acc23;
            }
            o0 += (float)acc01[0]; o1 += (float)acc01[1];
            o2 += (float)acc23[0]; o3 += (float)acc23[1];
        }
    }
    if (sq) {
        float4 p; p.x = o0; p.y = o1; p.z = o2; p.w = o3;
        *(float4*)&s_part[(sq - 1) * SS + n0] = p;
    }
    __syncthreads();
    if (!sq) {
        #pragma unroll
        for (int q = 0; q < 7; ++q) {
            float4 p = *(const float4*)&s_part[q * SS + n0];
            o0 += p.x; o1 += p.y; o2 += p.z; o3 += p.w;
        }
        float4 qb = *(const float4*)(qWob + (size_t)bt * HD + n0);
        float4 ov;
        ov.x = tanh_e(o0 + qb.x); ov.y = tanh_e(o1 + qb.y);
        ov.z = tanh_e(o2 + qb.z); ov.w = tanh_e(o3 + qb.w);
        *(float4*)(out + (size_t)bt * HD + n0) = ov;
    }
}

extern "C" void kernel_launch(void* const* d_in, const int* in_sizes, int n_in,
                              void* d_out, int out_size, void* d_ws, size_t ws_size,
                              hipStream_t stream) {
    (void)in_sizes; (void)n_in; (void)out_size; (void)ws_size;
    const float* query = (const float*)d_in[0];   // (B,T,H)
    const float* enc   = (const float*)d_in[1];   // (B,S,H)
    const int*   lens  = (const int*)d_in[2];     // (B,)
    const float* W_h   = (const float*)d_in[3];   // (H,H)
    const float* W_s   = (const float*)d_in[4];   // (H,H)
    const float* v     = (const float*)d_in[5];   // (H,)
    const float* W_out = (const float*)d_in[6];   // (2H,H)
    float* out = (float*)d_out;

    // workspace layout (~12 MB)
    ushort_t* WTs   = (ushort_t*)d_ws;                          // 512 KB
    ushort_t* WTh   = WTs + (size_t)HD * HD;                    // 512 KB
    ushort_t* WTo   = WTh + (size_t)HD * HD;                    // 1 MB
    ushort_t* encB  = WTo + (size_t)HD * 2 * HD;                // 2 MB (bf16 enc)
    float2*   tqa   = (float2*)(encB + (size_t)BB * SS * HD);   // 2 MB {tanh(pq), v*tanh(pq)}
    _Float16* peT   = (_Float16*)(tqa + (size_t)BB * TT * HD);  // 2 MB fp16 tanh(pe)^T
    _Float16* encWo = peT + (size_t)BB * HD * SS;               // 2 MB fp16 enc@Wo_a
    float*    qWob  = (float*)(encWo + (size_t)BB * SS * HD);   // 1 MB fp32 q@Wo_b
    ushort_t* cq    = (ushort_t*)(qWob + (size_t)BB * TT * HD); // 1 MB (query bf16, right half)

    wtrans_kernel<<<dim3(768), 256, 0, stream>>>(W_s, W_h, W_out, query, enc,
                                                 WTs, WTh, WTo, cq, encB);
    proj_kernel<<<dim3(80, 8), 256, 0, stream>>>(cq, encB, WTs, WTh, WTo, v,
                                                 tqa, peT, encWo, qWob);
    fused_kernel<<<dim3(BB * TT), 1024, 0, stream>>>(tqa, peT, v, encWo, qWob, lens, out);
}

// Round 5
// 112.533 us; speedup vs baseline: 1.3491x; 1.0502x over previous
//
#include <hip/hip_runtime.h>
#include <math.h>

#define HD 512
#define BB 4
#define TT 128
#define SS 512

typedef __attribute__((ext_vector_type(8))) short short8;
typedef __attribute__((ext_vector_type(4))) float floatx4;
typedef _Float16 half2_t __attribute__((ext_vector_type(2)));
typedef unsigned short ushort_t;
typedef unsigned int uint_t;

__device__ __forceinline__ float tanh_e(float x) {
    float t = __builtin_amdgcn_rcpf(__expf(2.f * x) + 1.f);
    return fmaf(-2.f, t, 1.f);
}
__device__ __forceinline__ ushort_t f2bf(float x) {      // RNE fp32->bf16
    unsigned int u = __float_as_uint(x);
    u += 0x7fffu + ((u >> 16) & 1u);
    return (ushort_t)(u >> 16);
}

// ---- Kernel 0: prep. W->bf16 [n][k] transposed (coalesced); query->cq right; enc->bf16 ----
// grid: 128 W-blocks (128k x 64n tiles) + 128 query blocks + 512 enc blocks = 768
__global__ __launch_bounds__(256) void wtrans_kernel(
    const float* __restrict__ Ws, const float* __restrict__ Wh,
    const float* __restrict__ Wo, const float* __restrict__ query,
    const float* __restrict__ enc,
    ushort_t* __restrict__ Ts, ushort_t* __restrict__ Th, ushort_t* __restrict__ To,
    ushort_t* __restrict__ cq, ushort_t* __restrict__ encB)
{
    const int bid = blockIdx.x;
    const int tid = threadIdx.x;
    if (bid < 128) {
        const float* src; ushort_t* dst; int K, l;
        if (bid < 32)      { src = Ws; dst = Ts; K = 512;  l = bid;      }
        else if (bid < 64) { src = Wh; dst = Th; K = 512;  l = bid - 32; }
        else               { src = Wo; dst = To; K = 1024; l = bid - 64; }
        const int ktiles = K >> 7;
        const int tk = l & (ktiles - 1), tn = l / ktiles;
        const int k0 = tk * 128, n0 = tn * 64;

        __shared__ ushort_t tile[64][136];     // [n][k], row 272B (16B aligned)

        const int lr  = tid >> 4;              // 0..15
        const int lc4 = (tid & 15) * 4;        // 0..60
        #pragma unroll
        for (int p = 0; p < 8; ++p) {
            const int row = p * 16 + lr;       // k-local
            float4 s = *(const float4*)(src + (size_t)(k0 + row) * HD + n0 + lc4);
            tile[lc4 + 0][row] = f2bf(s.x);
            tile[lc4 + 1][row] = f2bf(s.y);
            tile[lc4 + 2][row] = f2bf(s.z);
            tile[lc4 + 3][row] = f2bf(s.w);
        }
        __syncthreads();
        const int n = tid >> 2, kc = (tid & 3) * 32;
        #pragma unroll
        for (int j = 0; j < 4; ++j) {
            uint4 o = *(const uint4*)&tile[n][kc + j * 8];
            *(uint4*)&dst[(size_t)(n0 + n) * K + k0 + kc + j * 8] = o;
        }
    } else if (bid < 256) {
        // query -> bf16 into cq[m][512 + h]
        const int idx = ((bid - 128) * 256 + tid) * 8;
        const int m = idx >> 9, h = idx & 511;
        float4 q0 = *(const float4*)(query + (size_t)m * HD + h);
        float4 q1 = *(const float4*)(query + (size_t)m * HD + h + 4);
        uint4 o;
        o.x = (uint_t)f2bf(q0.x) | ((uint_t)f2bf(q0.y) << 16);
        o.y = (uint_t)f2bf(q0.z) | ((uint_t)f2bf(q0.w) << 16);
        o.z = (uint_t)f2bf(q1.x) | ((uint_t)f2bf(q1.y) << 16);
        o.w = (uint_t)f2bf(q1.z) | ((uint_t)f2bf(q1.w) << 16);
        *(uint4*)&cq[(size_t)m * 1024 + 512 + h] = o;
    } else {
        // enc -> bf16 encB (row-major)
        const size_t idx = ((size_t)(bid - 256) * 256 + tid) * 8;
        float4 e0 = *(const float4*)(enc + idx);
        float4 e1 = *(const float4*)(enc + idx + 4);
        uint4 o;
        o.x = (uint_t)f2bf(e0.x) | ((uint_t)f2bf(e0.y) << 16);
        o.y = (uint_t)f2bf(e0.z) | ((uint_t)f2bf(e0.w) << 16);
        o.z = (uint_t)f2bf(e1.x) | ((uint_t)f2bf(e1.y) << 16);
        o.w = (uint_t)f2bf(e1.z) | ((uint_t)f2bf(e1.w) << 16);
        *(uint4*)&encB[idx] = o;
    }
}

// ---- Kernel 1: MFMA proj, 4 GEMM families in one launch (grid 80 x 8):
//   bm  0..7 : tqa  = {tanh(q@Ws), v*tanh(q@Ws)}  fp32 pairs
//   bm 8..39 : peT  = fp16(tanh(enc@Wh))^T  (B,H,S)
//   bm 40..71: encWo= fp16(enc@Wo_a)        (B,S,H) row-major
//   bm 72..79: qWob = fp32(q@Wo_b)          (B*T,H)
#define LDP 40
__global__ __launch_bounds__(256) void proj_kernel(
    const ushort_t* __restrict__ cq, const ushort_t* __restrict__ encB,
    const ushort_t* __restrict__ WTs, const ushort_t* __restrict__ WTh,
    const ushort_t* __restrict__ WTo, const float* __restrict__ v,
    float2* __restrict__ tqa, _Float16* __restrict__ peT,
    _Float16* __restrict__ encWo, float* __restrict__ qWob)
{
    const int bm = blockIdx.x;            // 0..79
    const int bn = blockIdx.y;            // 0..7
    int type; const ushort_t* A; int lda; const ushort_t* B; int ldb; int m0;
    if (bm < 8)       { type = 0; A = cq + 512; lda = 1024; B = WTs;       ldb = 512;  m0 = bm * 64;        }
    else if (bm < 40) { type = 1; A = encB;     lda = 512;  B = WTh;       ldb = 512;  m0 = (bm - 8) * 64;  }
    else if (bm < 72) { type = 2; A = encB;     lda = 512;  B = WTo;       ldb = 1024; m0 = (bm - 40) * 64; }
    else              { type = 3; A = cq + 512; lda = 1024; B = WTo + 512; ldb = 1024; m0 = (bm - 72) * 64; }
    const int n0 = bn * 64;

    __shared__ ushort_t As[64 * LDP];     // [m][k]
    __shared__ ushort_t Bs[64 * LDP];     // [n][k]

    const int tid = threadIdx.x;
    const int lane = tid & 63, w = tid >> 6;
    const int quad = lane >> 4, lrow = lane & 15;
    const int mw = (w & 1) * 32, nw = (w >> 1) * 32;

    const int ar = tid >> 2;              // 0..63
    const int ac = (tid & 3) * 8;         // 0,8,16,24

    floatx4 zero = {0.f, 0.f, 0.f, 0.f};
    floatx4 acc[2][2] = {{zero, zero}, {zero, zero}};

    uint4 ald = *(const uint4*)&A[(size_t)(m0 + ar) * lda + ac];
    uint4 bld = *(const uint4*)&B[(size_t)(n0 + ar) * ldb + ac];

    for (int k0 = 0; k0 < HD; k0 += 32) {
        __syncthreads();
        *(uint4*)&As[ar * LDP + ac] = ald;
        *(uint4*)&Bs[ar * LDP + ac] = bld;
        __syncthreads();
        if (k0 + 32 < HD) {
            ald = *(const uint4*)&A[(size_t)(m0 + ar) * lda + k0 + 32 + ac];
            bld = *(const uint4*)&B[(size_t)(n0 + ar) * ldb + k0 + 32 + ac];
        }
        short8 af[2], bf[2];
        #pragma unroll
        for (int i = 0; i < 2; ++i)
            af[i] = *(const short8*)&As[(mw + i * 16 + lrow) * LDP + quad * 8];
        #pragma unroll
        for (int j = 0; j < 2; ++j)
            bf[j] = *(const short8*)&Bs[(nw + j * 16 + lrow) * LDP + quad * 8];
        #pragma unroll
        for (int i = 0; i < 2; ++i)
            #pragma unroll
            for (int j = 0; j < 2; ++j)
                acc[i][j] = __builtin_amdgcn_mfma_f32_16x16x32_bf16(af[i], bf[j], acc[i][j], 0, 0, 0);
    }

    if (type == 0) {
        #pragma unroll
        for (int j = 0; j < 2; ++j) {
            const int col = n0 + nw + j * 16 + lrow;
            const float vj = v[col];
            #pragma unroll
            for (int i = 0; i < 2; ++i)
                #pragma unroll
                for (int r = 0; r < 4; ++r) {
                    const int row = m0 + mw + i * 16 + quad * 4 + r;
                    float tq = tanh_e(acc[i][j][r]);
                    float2 o; o.x = tq; o.y = vj * tq;
                    tqa[(size_t)row * HD + col] = o;
                }
        }
    } else if (type == 1) {
        #pragma unroll
        for (int i = 0; i < 2; ++i)
            #pragma unroll
            for (int j = 0; j < 2; ++j) {
                const int gm = m0 + mw + i * 16 + quad * 4;
                const int b = gm >> 9, s = gm & 511;
                const int col = n0 + nw + j * 16 + lrow;
                _Float16 t0 = (_Float16)tanh_e(acc[i][j][0]);
                _Float16 t1 = (_Float16)tanh_e(acc[i][j][1]);
                _Float16 t2 = (_Float16)tanh_e(acc[i][j][2]);
                _Float16 t3 = (_Float16)tanh_e(acc[i][j][3]);
                ushort4 o;
                o.x = *(ushort_t*)&t0; o.y = *(ushort_t*)&t1;
                o.z = *(ushort_t*)&t2; o.w = *(ushort_t*)&t3;
                *(ushort4*)((ushort_t*)peT + ((size_t)b * HD + col) * SS + s) = o;
            }
    } else if (type == 2) {
        // encWo[b*S+s][n] fp16 row-major
        #pragma unroll
        for (int i = 0; i < 2; ++i)
            #pragma unroll
            for (int j = 0; j < 2; ++j) {
                const int col = n0 + nw + j * 16 + lrow;
                #pragma unroll
                for (int r = 0; r < 4; ++r) {
                    const int gm = m0 + mw + i * 16 + quad * 4 + r;
                    encWo[(size_t)gm * HD + col] = (_Float16)acc[i][j][r];
                }
            }
    } else {
        // qWob[b*T+t][n] fp32 (no activation)
        #pragma unroll
        for (int i = 0; i < 2; ++i)
            #pragma unroll
            for (int j = 0; j < 2; ++j) {
                const int col = n0 + nw + j * 16 + lrow;
                #pragma unroll
                for (int r = 0; r < 4; ++r) {
                    const int gm = m0 + mw + i * 16 + quad * 4 + r;
                    qWob[(size_t)gm * HD + col] = acc[i][j][r];
                }
            }
    }
}

// ---- Kernel 2: fused score + softmax + output. One block (1024 thr) per t-PAIR. ----
//  grid 256 (= 1 block/CU). Each thread computes BOTH t of the pair from one
//  peT/encWo read (halves L2 traffic). Phase A: thread = 8 s x 32 h x 2 t,
//  uint4 peT loads. Phase C: thread = 4 n x 64 s x 2 t. 16-slab symmetric
//  LDS combine. Packed-fp16 math; rcp + accumulation f32.
__global__ __launch_bounds__(1024, 4) void fused_kernel(
    const float2* __restrict__ tqa, const _Float16* __restrict__ peT,
    const float* __restrict__ vv, const _Float16* __restrict__ encWo,
    const float* __restrict__ qWob, const int* __restrict__ lens,
    float* __restrict__ out)
{
    const int bt0 = blockIdx.x * 2;               // pair (bt0, bt0+1), same batch
    const int b = bt0 >> 7;
    const int tid = threadIdx.x;                  // 0..1023
    const int lane = tid & 63, wid = tid >> 6;    // wid 0..15
    const int len = lens[b];

    __shared__ uint4  s_tab[2][HD];               // 16 KB {tq2,v2,vt2,-} per t
    __shared__ float  s_part[16][2][SS];          // 64 KB combine slabs (A: 16, C: 8)
    __shared__ float  s_sc[2][SS];                // 4 KB scores
    __shared__ uint_t s_al2[SS][2];               // 4 KB fp16 alpha pairs [s][t]
    __shared__ float  s_red[32];

    // build broadcast tables: one (t,h) per thread
    {
        const int t_loc = tid >> 9, h = tid & 511;
        float2 q = tqa[(size_t)(bt0 + t_loc) * HD + h];
        float vh = vv[h];
        _Float16 tqh = (_Float16)q.x, vvh = (_Float16)vh, vth = (_Float16)q.y;
        uint_t ta = *(ushort_t*)&tqh, tb = *(ushort_t*)&vvh, tc = *(ushort_t*)&vth;
        uint4 e4; e4.x = ta | (ta << 16); e4.y = tb | (tb << 16); e4.z = tc | (tc << 16); e4.w = 0;
        s_tab[t_loc][h] = e4;
    }
    __syncthreads();

    // ---- phase A: thread = (sg: 8 s) x (slice wid: 32 h) x 2 t ----
    const int sg = tid & 63;
    const int hq = (tid >> 6) & 7, sub = tid >> 9;
    const int s0 = sg * 8;
    const int hbase = hq * 64 + sub * 32;
    float p0[8] = {0.f,0.f,0.f,0.f,0.f,0.f,0.f,0.f};
    float p1[8] = {0.f,0.f,0.f,0.f,0.f,0.f,0.f,0.f};
    if (s0 < len) {
        const ushort_t* colp = (const ushort_t*)peT + ((size_t)b * HD + hbase) * SS + s0;
        const uint4* tp0 = &s_tab[0][hbase];
        const uint4* tp1 = &s_tab[1][hbase];
        half2_t one2; one2[0] = (_Float16)1.f; one2[1] = (_Float16)1.f;
        #pragma unroll 2
        for (int i = 0; i < 16; ++i) {            // 2 h per iter
            uint4 pA = *(const uint4*)(colp);
            uint4 pB = *(const uint4*)(colp + SS);
            colp += 2 * SS;
            uint4 cA0 = tp0[2 * i], cB0 = tp0[2 * i + 1];
            uint4 cA1 = tp1[2 * i], cB1 = tp1[2 * i + 1];
            half2_t teA0 = *(half2_t*)&pA.x, teA1 = *(half2_t*)&pA.y;
            half2_t teA2 = *(half2_t*)&pA.z, teA3 = *(half2_t*)&pA.w;
            half2_t teB0 = *(half2_t*)&pB.x, teB1 = *(half2_t*)&pB.y;
            half2_t teB2 = *(half2_t*)&pB.z, teB3 = *(half2_t*)&pB.w;
            // t0
            {
                half2_t tqA = *(half2_t*)&cA0.x, vA = *(half2_t*)&cA0.y, vtA = *(half2_t*)&cA0.z;
                half2_t tqB = *(half2_t*)&cB0.x, vB = *(half2_t*)&cB0.y, vtB = *(half2_t*)&cB0.z;
                half2_t dA0 = tqA * teA0 + one2, dA1 = tqA * teA1 + one2;
                half2_t dA2 = tqA * teA2 + one2, dA3 = tqA * teA3 + one2;
                half2_t dB0 = tqB * teB0 + one2, dB1 = tqB * teB1 + one2;
                half2_t dB2 = tqB * teB2 + one2, dB3 = tqB * teB3 + one2;
                half2_t mA0 = vA * teA0 + vtA, mA1 = vA * teA1 + vtA;
                half2_t mA2 = vA * teA2 + vtA, mA3 = vA * teA3 + vtA;
                half2_t mB0 = vB * teB0 + vtB, mB1 = vB * teB1 + vtB;
                half2_t mB2 = vB * teB2 + vtB, mB3 = vB * teB3 + vtB;
                half2_t n0h = mA0 * dB0 + mB0 * dA0, n1h = mA1 * dB1 + mB1 * dA1;
                half2_t n2h = mA2 * dB2 + mB2 * dA2, n3h = mA3 * dB3 + mB3 * dA3;
                half2_t d0h = dA0 * dB0, d1h = dA1 * dB1;
                half2_t d2h = dA2 * dB2, d3h = dA3 * dB3;
                p0[0] = fmaf((float)n0h[0], __builtin_amdgcn_rcpf((float)d0h[0]), p0[0]);
                p0[1] = fmaf((float)n0h[1], __builtin_amdgcn_rcpf((float)d0h[1]), p0[1]);
                p0[2] = fmaf((float)n1h[0], __builtin_amdgcn_rcpf((float)d1h[0]), p0[2]);
                p0[3] = fmaf((float)n1h[1], __builtin_amdgcn_rcpf((float)d1h[1]), p0[3]);
                p0[4] = fmaf((float)n2h[0], __builtin_amdgcn_rcpf((float)d2h[0]), p0[4]);
                p0[5] = fmaf((float)n2h[1], __builtin_amdgcn_rcpf((float)d2h[1]), p0[5]);
                p0[6] = fmaf((float)n3h[0], __builtin_amdgcn_rcpf((float)d3h[0]), p0[6]);
                p0[7] = fmaf((float)n3h[1], __builtin_amdgcn_rcpf((float)d3h[1]), p0[7]);
            }
            // t1
            {
                half2_t tqA = *(half2_t*)&cA1.x, vA = *(half2_t*)&cA1.y, vtA = *(half2_t*)&cA1.z;
                half2_t tqB = *(half2_t*)&cB1.x, vB = *(half2_t*)&cB1.y, vtB = *(half2_t*)&cB1.z;
                half2_t dA0 = tqA * teA0 + one2, dA1 = tqA * teA1 + one2;
                half2_t dA2 = tqA * teA2 + one2, dA3 = tqA * teA3 + one2;
                half2_t dB0 = tqB * teB0 + one2, dB1 = tqB * teB1 + one2;
                half2_t dB2 = tqB * teB2 + one2, dB3 = tqB * teB3 + one2;
                half2_t mA0 = vA * teA0 + vtA, mA1 = vA * teA1 + vtA;
                half2_t mA2 = vA * teA2 + vtA, mA3 = vA * teA3 + vtA;
                half2_t mB0 = vB * teB0 + vtB, mB1 = vB * teB1 + vtB;
                half2_t mB2 = vB * teB2 + vtB, mB3 = vB * teB3 + vtB;
                half2_t n0h = mA0 * dB0 + mB0 * dA0, n1h = mA1 * dB1 + mB1 * dA1;
                half2_t n2h = mA2 * dB2 + mB2 * dA2, n3h = mA3 * dB3 + mB3 * dA3;
                half2_t d0h = dA0 * dB0, d1h = dA1 * dB1;
                half2_t d2h = dA2 * dB2, d3h = dA3 * dB3;
                p1[0] = fmaf((float)n0h[0], __builtin_amdgcn_rcpf((float)d0h[0]), p1[0]);
                p1[1] = fmaf((float)n0h[1], __builtin_amdgcn_rcpf((float)d0h[1]), p1[1]);
                p1[2] = fmaf((float)n1h[0], __builtin_amdgcn_rcpf((float)d1h[0]), p1[2]);
                p1[3] = fmaf((float)n1h[1], __builtin_amdgcn_rcpf((float)d1h[1]), p1[3]);
                p1[4] = fmaf((float)n2h[0], __builtin_amdgcn_rcpf((float)d2h[0]), p1[4]);
                p1[5] = fmaf((float)n2h[1], __builtin_amdgcn_rcpf((float)d2h[1]), p1[5]);
                p1[6] = fmaf((float)n3h[0], __builtin_amdgcn_rcpf((float)d3h[0]), p1[6]);
                p1[7] = fmaf((float)n3h[1], __builtin_amdgcn_rcpf((float)d3h[1]), p1[7]);
            }
        }
    }
    // write own slab (slice id == wid)
    {
        float4 w0; w0.x = p0[0]; w0.y = p0[1]; w0.z = p0[2]; w0.w = p0[3];
        float4 w1; w1.x = p0[4]; w1.y = p0[5]; w1.z = p0[6]; w1.w = p0[7];
        *(float4*)&s_part[wid][0][s0]     = w0;
        *(float4*)&s_part[wid][0][s0 + 4] = w1;
        float4 w2; w2.x = p1[0]; w2.y = p1[1]; w2.z = p1[2]; w2.w = p1[3];
        float4 w3; w3.x = p1[4]; w3.y = p1[5]; w3.z = p1[6]; w3.w = p1[7];
        *(float4*)&s_part[wid][1][s0]     = w2;
        *(float4*)&s_part[wid][1][s0 + 4] = w3;
    }
    __syncthreads();
    // symmetric combine: thread = (t, s)
    {
        const int t_loc = tid >> 9, s = tid & 511;
        float acc = 0.f;
        #pragma unroll
        for (int q = 0; q < 16; ++q) acc += s_part[q][t_loc][s];
        s_sc[t_loc][s] = (s < len) ? acc : -INFINITY;
    }
    __syncthreads();

    // ---- phase B: masked softmax per t over 512 s; thread = (t, s) ----
    {
        const int t_loc = tid >> 9;
        float sc = s_sc[t_loc][tid & 511];
        float m = sc;
        #pragma unroll
        for (int off = 32; off; off >>= 1) m = fmaxf(m, __shfl_xor(m, off, 64));
        if (lane == 0) s_red[wid] = m;
        __syncthreads();
        const int rb = (t_loc << 3);
        m = s_red[rb];
        #pragma unroll
        for (int i2 = 1; i2 < 8; ++i2) m = fmaxf(m, s_red[rb + i2]);

        float e = __expf(sc - m);                 // exp(-inf)=0 handles mask
        float sum = e;
        #pragma unroll
        for (int off = 32; off; off >>= 1) sum += __shfl_xor(sum, off, 64);
        if (lane == 0) s_red[16 + wid] = sum;
        __syncthreads();
        float total = s_red[16 + rb];
        #pragma unroll
        for (int i2 = 1; i2 < 8; ++i2) total += s_red[16 + rb + i2];
        float a = e * __builtin_amdgcn_rcpf(total);
        _Float16 ah = (_Float16)a;
        uint_t ap = *(ushort_t*)&ah;
        s_al2[tid & 511][t_loc] = ap | (ap << 16);   // 0 past len
    }
    __syncthreads();

    // ---- phase C: thread = (ng: 4 n) x (sq: 64 s) x 2 t; fp16 chunk accum ----
    const int ng = tid & 127, sq = tid >> 7;      // sq 0..7
    const int n0 = ng * 4;
    const int sbeg = sq * 64;
    float fo0[4] = {0.f, 0.f, 0.f, 0.f};
    float fo1[4] = {0.f, 0.f, 0.f, 0.f};
    {
        const ushort_t* ew = (const ushort_t*)encWo + ((size_t)b * SS + sbeg) * HD + n0;
        const int rem = (len > sbeg) ? ((len - sbeg < 64) ? len - sbeg : 64) : 0;
        const int schunks = (rem + 7) >> 3;       // alpha==0 past len -> full chunks safe
        for (int c = 0; c < schunks; ++c) {
            half2_t a01_0, a23_0, a01_1, a23_1;
            a01_0[0] = (_Float16)0.f; a01_0[1] = (_Float16)0.f;
            a23_0 = a01_0; a01_1 = a01_0; a23_1 = a01_0;
            const ushort_t* ewc = ew + (size_t)(c * 8) * HD;
            #pragma unroll
            for (int k = 0; k < 8; ++k) {
                uint2 wv = *(const uint2*)(ewc + (size_t)k * HD);
                uint2 av = *(const uint2*)&s_al2[sbeg + c * 8 + k][0];
                half2_t w01 = *(half2_t*)&wv.x, w23 = *(half2_t*)&wv.y;
                half2_t al0 = *(half2_t*)&av.x, al1 = *(half2_t*)&av.y;
                a01_0 = al0 * w01 + a01_0; a23_0 = al0 * w23 + a23_0;
                a01_1 = al1 * w01 + a01_1; a23_1 = al1 * w23 + a23_1;
            }
            fo0[0] += (float)a01_0[0]; fo0[1] += (float)a01_0[1];
            fo0[2] += (float)a23_0[0]; fo0[3] += (float)a23_0[1];
            fo1[0] += (float)a01_1[0]; fo1[1] += (float)a01_1[1];
            fo1[2] += (float)a23_1[0]; fo1[3] += (float)a23_1[1];
        }
    }
    __syncthreads();                              // s_part reuse barrier
    {
        float4 w0; w0.x = fo0[0]; w0.y = fo0[1]; w0.z = fo0[2]; w0.w = fo0[3];
        float4 w1; w1.x = fo1[0]; w1.y = fo1[1]; w1.z = fo1[2]; w1.w = fo1[3];
        *(float4*)&s_part[sq][0][n0] = w0;
        *(float4*)&s_part[sq][1][n0] = w1;
    }
    __syncthreads();
    // symmetric combine + epilogue: thread = (t, n)
    {
        const int t_loc = tid >> 9, n = tid & 511;
        float acc = 0.f;
        #pragma unroll
        for (int q = 0; q < 8; ++q) acc += s_part[q][t_loc][n];
        acc += qWob[(size_t)(bt0 + t_loc) * HD + n];
        out[(size_t)(bt0 + t_loc) * HD + n] = tanh_e(acc);
    }
}

extern "C" void kernel_launch(void* const* d_in, const int* in_sizes, int n_in,
                              void* d_out, int out_size, void* d_ws, size_t ws_size,
                              hipStream_t stream) {
    (void)in_sizes; (void)n_in; (void)out_size; (void)ws_size;
    const float* query = (const float*)d_in[0];   // (B,T,H)
    const float* enc   = (const float*)d_in[1];   // (B,S,H)
    const int*   lens  = (const int*)d_in[2];     // (B,)
    const float* W_h   = (const float*)d_in[3];   // (H,H)
    const float* W_s   = (const float*)d_in[4];   // (H,H)
    const float* v     = (const float*)d_in[5];   // (H,)
    const float* W_out = (const float*)d_in[6];   // (2H,H)
    float* out = (float*)d_out;

    // workspace layout (~12 MB)
    ushort_t* WTs   = (ushort_t*)d_ws;                          // 512 KB
    ushort_t* WTh   = WTs + (size_t)HD * HD;                    // 512 KB
    ushort_t* WTo   = WTh + (size_t)HD * HD;                    // 1 MB
    ushort_t* encB  = WTo + (size_t)HD * 2 * HD;                // 2 MB (bf16 enc)
    float2*   tqa   = (float2*)(encB + (size_t)BB * SS * HD);   // 2 MB {tanh(pq), v*tanh(pq)}
    _Float16* peT   = (_Float16*)(tqa + (size_t)BB * TT * HD);  // 2 MB fp16 tanh(pe)^T
    _Float16* encWo = peT + (size_t)BB * HD * SS;               // 2 MB fp16 enc@Wo_a
    float*    qWob  = (float*)(encWo + (size_t)BB * SS * HD);   // 1 MB fp32 q@Wo_b
    ushort_t* cq    = (ushort_t*)(qWob + (size_t)BB * TT * HD); // 1 MB (query bf16, right half)

    wtrans_kernel<<<dim3(768), 256, 0, stream>>>(W_s, W_h, W_out, query, enc,
                                                 WTs, WTh, WTo, cq, encB);
    proj_kernel<<<dim3(80, 8), 256, 0, stream>>>(cq, encB, WTs, WTh, WTo, v,
                                                 tqa, peT, encWo, qWob);
    fused_kernel<<<dim3(BB * TT / 2), 1024, 0, stream>>>(tqa, peT, v, encWo, qWob, lens, out);
}